// Round 1
// baseline (757.213 us; speedup 1.0000x reference)
//
#include <hip/hip_runtime.h>
#include <hip/hip_bf16.h>
#include <math.h>

// GNNStack: 3x GAT(heads=1, hid=64) + relu, then 64->64, 64->47, log_softmax.
// Strategy:
//  - Build CSR (edges grouped by dst) ONCE per call: histogram -> scan -> scatter.
//  - Per layer: LIN kernel (h = x@W+b, alpha_l/r dot products), AGG kernel
//    (one wave per dst node: segment max, exp-sum, weighted gather-accumulate,
//    fused relu). No float atomics anywhere.
//  - POST kernel: fused 64x64 GEMM + 64x47 GEMM + log_softmax, one wave/node.

#define IN_DIM 128
#define HID 64
#define OUT_DIM 47
#define NEG_SLOPE 0.2f
#define EPS 1e-16f
#define SCAN_TILE 1024

__global__ __launch_bounds__(256) void hist_kernel(const int* __restrict__ dst,
                                                   int* __restrict__ cnt, int e) {
    int i = blockIdx.x * 256 + threadIdx.x;
    if (i < e) atomicAdd(&cnt[dst[i]], 1);
}

__global__ __launch_bounds__(256) void scan1_kernel(const int* __restrict__ cnt,
                                                    int* __restrict__ rowptr,
                                                    int* __restrict__ bsum, int n) {
    __shared__ int ts[256];
    int tid = threadIdx.x;
    int base = blockIdx.x * SCAN_TILE + tid * 4;
    int v[4];
#pragma unroll
    for (int t = 0; t < 4; t++) v[t] = (base + t < n) ? cnt[base + t] : 0;
    int tsum = v[0] + v[1] + v[2] + v[3];
    ts[tid] = tsum;
    __syncthreads();
    for (int off = 1; off < 256; off <<= 1) {
        int t = (tid >= off) ? ts[tid - off] : 0;
        __syncthreads();
        ts[tid] += t;
        __syncthreads();
    }
    int excl = ts[tid] - tsum;
#pragma unroll
    for (int t = 0; t < 4; t++) {
        if (base + t < n) rowptr[base + t] = excl;
        excl += v[t];
    }
    if (tid == 255) bsum[blockIdx.x] = ts[255];
}

__global__ void scan2_kernel(int* bsum, int nb) {
    if (threadIdx.x == 0 && blockIdx.x == 0) {
        int run = 0;
        for (int i = 0; i < nb; i++) { int t = bsum[i]; bsum[i] = run; run += t; }
    }
}

__global__ __launch_bounds__(256) void scan3_kernel(int* __restrict__ rowptr,
                                                    const int* __restrict__ bsum,
                                                    int* __restrict__ off, int n, int e) {
    int base = blockIdx.x * SCAN_TILE + threadIdx.x * 4;
    int add = bsum[blockIdx.x];
#pragma unroll
    for (int t = 0; t < 4; t++) {
        if (base + t < n) {
            int r = rowptr[base + t] + add;
            rowptr[base + t] = r;
            off[base + t] = r;
        }
    }
    if (blockIdx.x == 0 && threadIdx.x == 0) rowptr[n] = e;
}

__global__ __launch_bounds__(256) void scatter_kernel(const int* __restrict__ src,
                                                      const int* __restrict__ dst,
                                                      int* __restrict__ off,
                                                      int* __restrict__ col, int e) {
    int i = blockIdx.x * 256 + threadIdx.x;
    if (i < e) {
        int d = dst[i];
        int p = atomicAdd(&off[d], 1);
        col[p] = src[i];
    }
}

// h = X @ W + b  (din x 64), alpha_l = h . attl, alpha_r = h . attr
template <int DIN>
__global__ __launch_bounds__(256) void lin_kernel(const float* __restrict__ X,
                                                  const float* __restrict__ W,
                                                  const float* __restrict__ B,
                                                  const float* __restrict__ attl,
                                                  const float* __restrict__ attr,
                                                  float* __restrict__ H,
                                                  float* __restrict__ AL,
                                                  float* __restrict__ AR, int n) {
    __shared__ float Wl[DIN * 64];
    __shared__ __align__(16) float xl[4][DIN];
    int tid = threadIdx.x;
    for (int i = tid; i < DIN * 64; i += 256) Wl[i] = W[i];
    __syncthreads();
    int lane = tid & 63, wv = tid >> 6;
    float bl = B[lane];
    float atl = attl[lane], atr = attr[lane];
    for (int nidx = blockIdx.x * 4 + wv; nidx < n; nidx += gridDim.x * 4) {
        const float* xr = X + (size_t)nidx * DIN;
#pragma unroll
        for (int t = 0; t < DIN / 64; t++) xl[wv][t * 64 + lane] = xr[t * 64 + lane];
        // wave-synchronous LDS use: same wave wrote xl[wv], lgkmcnt ordering
        // is inserted by the compiler; no cross-wave sharing.
        float acc = bl;
#pragma unroll 8
        for (int k4 = 0; k4 < DIN; k4 += 4) {
            float4 xv = *(const float4*)&xl[wv][k4];
            acc = fmaf(xv.x, Wl[(k4 + 0) * 64 + lane], acc);
            acc = fmaf(xv.y, Wl[(k4 + 1) * 64 + lane], acc);
            acc = fmaf(xv.z, Wl[(k4 + 2) * 64 + lane], acc);
            acc = fmaf(xv.w, Wl[(k4 + 3) * 64 + lane], acc);
        }
        H[(size_t)nidx * 64 + lane] = acc;
        float pl = acc * atl, pr = acc * atr;
#pragma unroll
        for (int o = 32; o; o >>= 1) {
            pl += __shfl_xor(pl, o, 64);
            pr += __shfl_xor(pr, o, 64);
        }
        if (lane == 0) {
            AL[nidx] = pl;
            AR[nidx] = pr;
        }
    }
}

// One wave per dst node: segment softmax + weighted aggregate + relu.
__global__ __launch_bounds__(256) void agg_kernel(const int* __restrict__ rowptr,
                                                  const int* __restrict__ col,
                                                  const float* __restrict__ AL,
                                                  const float* __restrict__ AR,
                                                  const float* __restrict__ H,
                                                  float* __restrict__ OUT, int n) {
    int wv = threadIdx.x >> 6, lane = threadIdx.x & 63;
    int nidx = blockIdx.x * 4 + wv;
    if (nidx >= n) return;
    int beg = rowptr[nidx], end = rowptr[nidx + 1];
    float ar_i = AR[nidx];
    // pass 1: segment max (lane-parallel over edges)
    float mx = -INFINITY;
    for (int j = beg + lane; j < end; j += 64) {
        float e = AL[col[j]] + ar_i;
        e = e > 0.f ? e : NEG_SLOPE * e;
        mx = fmaxf(mx, e);
    }
#pragma unroll
    for (int o = 32; o; o >>= 1) mx = fmaxf(mx, __shfl_xor(mx, o, 64));
    // pass 2: serial over edges, vector over channels (lane = channel)
    float denom = 0.f, acc = 0.f;
    int j = beg;
    for (; j + 4 <= end; j += 4) {
        int s0 = col[j], s1 = col[j + 1], s2 = col[j + 2], s3 = col[j + 3];
        float e0 = AL[s0] + ar_i, e1 = AL[s1] + ar_i, e2 = AL[s2] + ar_i, e3 = AL[s3] + ar_i;
        e0 = e0 > 0.f ? e0 : NEG_SLOPE * e0;
        e1 = e1 > 0.f ? e1 : NEG_SLOPE * e1;
        e2 = e2 > 0.f ? e2 : NEG_SLOPE * e2;
        e3 = e3 > 0.f ? e3 : NEG_SLOPE * e3;
        float x0 = __expf(e0 - mx), x1 = __expf(e1 - mx);
        float x2 = __expf(e2 - mx), x3 = __expf(e3 - mx);
        float h0v = H[(size_t)s0 * 64 + lane];
        float h1v = H[(size_t)s1 * 64 + lane];
        float h2v = H[(size_t)s2 * 64 + lane];
        float h3v = H[(size_t)s3 * 64 + lane];
        denom += x0 + x1 + x2 + x3;
        acc = fmaf(x0, h0v, acc);
        acc = fmaf(x1, h1v, acc);
        acc = fmaf(x2, h2v, acc);
        acc = fmaf(x3, h3v, acc);
    }
    for (; j < end; ++j) {
        int s = col[j];
        float e = AL[s] + ar_i;
        e = e > 0.f ? e : NEG_SLOPE * e;
        float ex = __expf(e - mx);
        denom += ex;
        acc = fmaf(ex, H[(size_t)s * 64 + lane], acc);
    }
    float o = acc / (denom + EPS);
    OUT[(size_t)nidx * 64 + lane] = o > 0.f ? o : 0.f;  // fused relu
}

// h3 @ Wp1 + bp1 -> p ; p @ Wp2 + bp2 -> q ; log_softmax(q)
__global__ __launch_bounds__(256) void post_kernel(const float* __restrict__ H3,
                                                   const float* __restrict__ Wp1,
                                                   const float* __restrict__ bp1,
                                                   const float* __restrict__ Wp2,
                                                   const float* __restrict__ bp2,
                                                   float* __restrict__ OUT, int n) {
    __shared__ float W1l[64 * 64];
    __shared__ float W2l[64 * 64];
    __shared__ __align__(16) float stage[4][64];
    int tid = threadIdx.x;
    for (int i = tid; i < 64 * 64; i += 256) {
        W1l[i] = Wp1[i];
        int k = i >> 6, jj = i & 63;
        W2l[i] = (jj < OUT_DIM) ? Wp2[k * OUT_DIM + jj] : 0.f;
    }
    __syncthreads();
    int lane = tid & 63, wv = tid >> 6;
    float b1 = bp1[lane];
    float b2 = (lane < OUT_DIM) ? bp2[lane] : 0.f;
    for (int nidx = blockIdx.x * 4 + wv; nidx < n; nidx += gridDim.x * 4) {
        float h = H3[(size_t)nidx * 64 + lane];
        stage[wv][lane] = h;
        float p = b1;
#pragma unroll 8
        for (int k4 = 0; k4 < 64; k4 += 4) {
            float4 hv = *(const float4*)&stage[wv][k4];
            p = fmaf(hv.x, W1l[(k4 + 0) * 64 + lane], p);
            p = fmaf(hv.y, W1l[(k4 + 1) * 64 + lane], p);
            p = fmaf(hv.z, W1l[(k4 + 2) * 64 + lane], p);
            p = fmaf(hv.w, W1l[(k4 + 3) * 64 + lane], p);
        }
        stage[wv][lane] = p;  // wave-synchronous overwrite after all reads
        float q = b2;
#pragma unroll 8
        for (int k4 = 0; k4 < 64; k4 += 4) {
            float4 pv = *(const float4*)&stage[wv][k4];
            q = fmaf(pv.x, W2l[(k4 + 0) * 64 + lane], q);
            q = fmaf(pv.y, W2l[(k4 + 1) * 64 + lane], q);
            q = fmaf(pv.z, W2l[(k4 + 2) * 64 + lane], q);
            q = fmaf(pv.w, W2l[(k4 + 3) * 64 + lane], q);
        }
        float qm = (lane < OUT_DIM) ? q : -INFINITY;
        float mxv = qm;
#pragma unroll
        for (int o = 32; o; o >>= 1) mxv = fmaxf(mxv, __shfl_xor(mxv, o, 64));
        float ex = (lane < OUT_DIM) ? __expf(q - mxv) : 0.f;
        float s = ex;
#pragma unroll
        for (int o = 32; o; o >>= 1) s += __shfl_xor(s, o, 64);
        float r = q - mxv - __logf(s);
        if (lane < OUT_DIM) OUT[(size_t)nidx * OUT_DIM + lane] = r;
    }
}

extern "C" void kernel_launch(void* const* d_in, const int* in_sizes, int n_in,
                              void* d_out, int out_size, void* d_ws, size_t ws_size,
                              hipStream_t stream) {
    const float* x = (const float*)d_in[0];
    const int* ei = (const int*)d_in[1];
    const float* W0 = (const float*)d_in[2];
    const float* b0 = (const float*)d_in[3];
    const float* al0 = (const float*)d_in[4];
    const float* ar0 = (const float*)d_in[5];
    const float* W1 = (const float*)d_in[6];
    const float* b1 = (const float*)d_in[7];
    const float* al1 = (const float*)d_in[8];
    const float* ar1 = (const float*)d_in[9];
    const float* W2 = (const float*)d_in[10];
    const float* b2 = (const float*)d_in[11];
    const float* al2 = (const float*)d_in[12];
    const float* ar2 = (const float*)d_in[13];
    const float* Wp1 = (const float*)d_in[14];
    const float* bp1 = (const float*)d_in[15];
    const float* Wp2 = (const float*)d_in[16];
    const float* bp2 = (const float*)d_in[17];
    float* out = (float*)d_out;

    const int N = in_sizes[0] / IN_DIM;
    const int E = in_sizes[1] / 2;
    const int NB = (N + SCAN_TILE - 1) / SCAN_TILE;

    char* ws = (char*)d_ws;
    float* h0 = (float*)ws;      ws += (size_t)N * 64 * sizeof(float);
    float* h1 = (float*)ws;      ws += (size_t)N * 64 * sizeof(float);
    float* ALb = (float*)ws;     ws += (size_t)N * sizeof(float);
    float* ARb = (float*)ws;     ws += (size_t)N * sizeof(float);
    int* rowptr = (int*)ws;      ws += (size_t)(N + 1) * sizeof(int);
    int* offb = (int*)ws;        ws += (size_t)N * sizeof(int);
    int* col = (int*)ws;         ws += (size_t)E * sizeof(int);
    int* bsum = (int*)ws;        ws += (size_t)NB * sizeof(int);

    const int* src = ei;
    const int* dst = ei + E;

    // ---- build CSR by dst ----
    hipMemsetAsync(offb, 0, (size_t)N * sizeof(int), stream);
    hist_kernel<<<(E + 255) / 256, 256, 0, stream>>>(dst, offb, E);
    scan1_kernel<<<NB, 256, 0, stream>>>(offb, rowptr, bsum, N);
    scan2_kernel<<<1, 64, 0, stream>>>(bsum, NB);
    scan3_kernel<<<NB, 256, 0, stream>>>(rowptr, bsum, offb, N, E);
    scatter_kernel<<<(E + 255) / 256, 256, 0, stream>>>(src, dst, offb, col, E);

    int agg_grid = (N + 3) / 4;

    // ---- layer 0 ----
    lin_kernel<IN_DIM><<<2048, 256, 0, stream>>>(x, W0, b0, al0, ar0, h0, ALb, ARb, N);
    agg_kernel<<<agg_grid, 256, 0, stream>>>(rowptr, col, ALb, ARb, h0, h1, N);
    // ---- layer 1 ----
    lin_kernel<HID><<<2048, 256, 0, stream>>>(h1, W1, b1, al1, ar1, h0, ALb, ARb, N);
    agg_kernel<<<agg_grid, 256, 0, stream>>>(rowptr, col, ALb, ARb, h0, h1, N);
    // ---- layer 2 ----
    lin_kernel<HID><<<2048, 256, 0, stream>>>(h1, W2, b2, al2, ar2, h0, ALb, ARb, N);
    agg_kernel<<<agg_grid, 256, 0, stream>>>(rowptr, col, ALb, ARb, h0, h1, N);
    // ---- post ----
    post_kernel<<<2048, 256, 0, stream>>>(h1, Wp1, bp1, Wp2, bp2, out, N);
}

// Round 2
// 575.347 us; speedup vs baseline: 1.3161x; 1.3161x over previous
//
#include <hip/hip_runtime.h>
#include <hip/hip_bf16.h>
#include <math.h>

// GNNStack: 3x GAT(heads=1, hid=64) + relu, then 64->64, 64->47, log_softmax.
//  - CSR build via two-level counting sort (no per-node global atomics,
//    coalesced staging writes, L2-local placement).
//  - AGG: one wave per dst node; edge data cached in registers; exp computed
//    lane-parallel; gather pass is shfl-broadcast + coalesced 256B H loads.

#define IN_DIM 128
#define HID 64
#define OUT_DIM 47
#define NEG_SLOPE 0.2f
#define EPS 1e-16f
#define BBITS 10
#define BN 1024
#define NBUCK_MAX 128

// ---- CSR build: bucket histogram ----
__global__ __launch_bounds__(256) void bucket_count_kernel(const int* __restrict__ dst,
                                                           int* __restrict__ bcnt,
                                                           int e, int nbuck) {
    __shared__ int h[NBUCK_MAX];
    int tid = threadIdx.x;
    if (tid < nbuck) h[tid] = 0;
    __syncthreads();
    int chunk = (e + gridDim.x - 1) / gridDim.x;
    int beg = blockIdx.x * chunk, end = min(e, beg + chunk);
    for (int i = beg + tid; i < end; i += 256) atomicAdd(&h[dst[i] >> BBITS], 1);
    __syncthreads();
    if (tid < nbuck && h[tid]) atomicAdd(&bcnt[tid], h[tid]);
}

__global__ void bucket_scan_kernel(const int* __restrict__ bcnt, int* __restrict__ bbase,
                                   int* __restrict__ bfill, int nbuck) {
    if (threadIdx.x == 0 && blockIdx.x == 0) {
        int run = 0;
        for (int i = 0; i < nbuck; i++) { bbase[i] = run; bfill[i] = run; run += bcnt[i]; }
        bbase[nbuck] = run;
    }
}

// ---- CSR build: bucketed scatter (coalesced runs into staging) ----
__global__ __launch_bounds__(256) void bucket_scatter_kernel(const int* __restrict__ src,
                                                             const int* __restrict__ dst,
                                                             int* __restrict__ bfill,
                                                             int2* __restrict__ stg,
                                                             int e, int nbuck) {
    __shared__ int lcnt[NBUCK_MAX], lfill[NBUCK_MAX];
    int tid = threadIdx.x;
    if (tid < nbuck) lcnt[tid] = 0;
    __syncthreads();
    int chunk = (e + gridDim.x - 1) / gridDim.x;
    int beg = blockIdx.x * chunk, end = min(e, beg + chunk);
    for (int i = beg + tid; i < end; i += 256) atomicAdd(&lcnt[dst[i] >> BBITS], 1);
    __syncthreads();
    if (tid < nbuck) lfill[tid] = lcnt[tid] ? atomicAdd(&bfill[tid], lcnt[tid]) : 0;
    __syncthreads();
    for (int i = beg + tid; i < end; i += 256) {
        int d = dst[i];
        int p = atomicAdd(&lfill[d >> BBITS], 1);
        stg[p] = make_int2(src[i], d);
    }
}

// ---- CSR build: per-bucket placement (LDS hist + scan, L2-local col writes) ----
__global__ __launch_bounds__(1024) void bucket_place_kernel(const int2* __restrict__ stg,
                                                            const int* __restrict__ bbase,
                                                            int* __restrict__ rowptr,
                                                            int* __restrict__ col,
                                                            int n, int e) {
    __shared__ int lcnt[BN];
    __shared__ int lscan[BN];
    __shared__ int lfill[BN];
    int tid = threadIdx.x, b = blockIdx.x;
    int node0 = b << BBITS;
    int ebeg = bbase[b], eend = bbase[b + 1];
    lcnt[tid] = 0;
    __syncthreads();
    for (int j = ebeg + tid; j < eend; j += 1024) atomicAdd(&lcnt[stg[j].y - node0], 1);
    __syncthreads();
    int v = lcnt[tid];
    lscan[tid] = v;
    __syncthreads();
    for (int off = 1; off < 1024; off <<= 1) {
        int t = (tid >= off) ? lscan[tid - off] : 0;
        __syncthreads();
        lscan[tid] += t;
        __syncthreads();
    }
    int gbase = ebeg + lscan[tid] - v;  // exclusive scan -> global edge base
    if (node0 + tid < n) rowptr[node0 + tid] = gbase;
    lfill[tid] = gbase;
    __syncthreads();
    for (int j = ebeg + tid; j < eend; j += 1024) {
        int2 ed = stg[j];
        int p = atomicAdd(&lfill[ed.y - node0], 1);
        col[p] = ed.x;
    }
    if (b == 0 && tid == 0) rowptr[n] = e;
}

// ---- h = X @ W + b, alpha_l = h.attl, alpha_r = h.attr ----
template <int DIN>
__global__ __launch_bounds__(256) void lin_kernel(const float* __restrict__ X,
                                                  const float* __restrict__ W,
                                                  const float* __restrict__ B,
                                                  const float* __restrict__ attl,
                                                  const float* __restrict__ attr,
                                                  float* __restrict__ H,
                                                  float* __restrict__ AL,
                                                  float* __restrict__ AR, int n) {
    __shared__ float Wl[DIN * 64];
    __shared__ __align__(16) float xl[4][DIN];
    int tid = threadIdx.x;
    for (int i = tid; i < DIN * 64; i += 256) Wl[i] = W[i];
    __syncthreads();
    int lane = tid & 63, wv = tid >> 6;
    float bl = B[lane];
    float atl = attl[lane], atr = attr[lane];
    for (int nidx = blockIdx.x * 4 + wv; nidx < n; nidx += gridDim.x * 4) {
        const float* xr = X + (size_t)nidx * DIN;
#pragma unroll
        for (int t = 0; t < DIN / 64; t++) xl[wv][t * 64 + lane] = xr[t * 64 + lane];
        float acc = bl;
#pragma unroll 8
        for (int k4 = 0; k4 < DIN; k4 += 4) {
            float4 xv = *(const float4*)&xl[wv][k4];
            acc = fmaf(xv.x, Wl[(k4 + 0) * 64 + lane], acc);
            acc = fmaf(xv.y, Wl[(k4 + 1) * 64 + lane], acc);
            acc = fmaf(xv.z, Wl[(k4 + 2) * 64 + lane], acc);
            acc = fmaf(xv.w, Wl[(k4 + 3) * 64 + lane], acc);
        }
        H[(size_t)nidx * 64 + lane] = acc;
        float pl = acc * atl, pr = acc * atr;
#pragma unroll
        for (int o = 32; o; o >>= 1) {
            pl += __shfl_xor(pl, o, 64);
            pr += __shfl_xor(pr, o, 64);
        }
        if (lane == 0) {
            AL[nidx] = pl;
            AR[nidx] = pr;
        }
    }
}

// ---- One wave per dst node: segment softmax + weighted aggregate + relu ----
__global__ __launch_bounds__(256) void agg_kernel(const int* __restrict__ rowptr,
                                                  const int* __restrict__ col,
                                                  const float* __restrict__ AL,
                                                  const float* __restrict__ AR,
                                                  const float* __restrict__ H,
                                                  float* __restrict__ OUT, int n) {
    int wv = threadIdx.x >> 6, lane = threadIdx.x & 63;
    int nidx = blockIdx.x * 4 + wv;
    if (nidx >= n) return;
    int beg = rowptr[nidx], end = rowptr[nidx + 1];
    int deg = end - beg;
    float ar_i = AR[nidx];
    // lane-parallel: load edges into registers (2 chunks of 64 cover deg<=128)
    int c0 = 0;
    float e0 = -INFINITY;
    if (lane < deg) {
        c0 = col[beg + lane];
        float t = AL[c0] + ar_i;
        e0 = t > 0.f ? t : NEG_SLOPE * t;
    }
    int c1 = 0;
    float e1 = -INFINITY;
    if (64 + lane < deg) {
        c1 = col[beg + 64 + lane];
        float t = AL[c1] + ar_i;
        e1 = t > 0.f ? t : NEG_SLOPE * t;
    }
    float mx = fmaxf(e0, e1);
    for (int j = beg + 128 + lane; j < end; j += 64) {  // cold path, deg>128
        float t = AL[col[j]] + ar_i;
        t = t > 0.f ? t : NEG_SLOPE * t;
        mx = fmaxf(mx, t);
    }
#pragma unroll
    for (int o = 32; o; o >>= 1) mx = fmaxf(mx, __shfl_xor(mx, o, 64));
    float x0 = (lane < deg) ? __expf(e0 - mx) : 0.f;
    float x1 = (64 + lane < deg) ? __expf(e1 - mx) : 0.f;
    float dl = x0 + x1;
    for (int j = beg + 128 + lane; j < end; j += 64) {  // cold path denom
        float t = AL[col[j]] + ar_i;
        t = t > 0.f ? t : NEG_SLOPE * t;
        dl += __expf(t - mx);
    }
#pragma unroll
    for (int o = 32; o; o >>= 1) dl += __shfl_xor(dl, o, 64);
    // gather pass: serial over edges, vector over channels (lane = channel)
    float acc = 0.f;
    int cnt0 = deg < 64 ? deg : 64;
    int k = 0;
    for (; k + 4 <= cnt0; k += 4) {
        float ea = __shfl(x0, k, 64), eb = __shfl(x0, k + 1, 64);
        float ec = __shfl(x0, k + 2, 64), ed = __shfl(x0, k + 3, 64);
        int sa = __shfl(c0, k, 64), sb = __shfl(c0, k + 1, 64);
        int sc = __shfl(c0, k + 2, 64), sd = __shfl(c0, k + 3, 64);
        float ha = H[(size_t)sa * 64 + lane];
        float hb = H[(size_t)sb * 64 + lane];
        float hc = H[(size_t)sc * 64 + lane];
        float hd = H[(size_t)sd * 64 + lane];
        acc = fmaf(ea, ha, acc);
        acc = fmaf(eb, hb, acc);
        acc = fmaf(ec, hc, acc);
        acc = fmaf(ed, hd, acc);
    }
    for (; k < cnt0; k++) {
        float ex = __shfl(x0, k, 64);
        int s = __shfl(c0, k, 64);
        acc = fmaf(ex, H[(size_t)s * 64 + lane], acc);
    }
    if (deg > 64) {
        int cnt1 = deg - 64 < 64 ? deg - 64 : 64;
        k = 0;
        for (; k + 4 <= cnt1; k += 4) {
            float ea = __shfl(x1, k, 64), eb = __shfl(x1, k + 1, 64);
            float ec = __shfl(x1, k + 2, 64), ed = __shfl(x1, k + 3, 64);
            int sa = __shfl(c1, k, 64), sb = __shfl(c1, k + 1, 64);
            int sc = __shfl(c1, k + 2, 64), sd = __shfl(c1, k + 3, 64);
            float ha = H[(size_t)sa * 64 + lane];
            float hb = H[(size_t)sb * 64 + lane];
            float hc = H[(size_t)sc * 64 + lane];
            float hd = H[(size_t)sd * 64 + lane];
            acc = fmaf(ea, ha, acc);
            acc = fmaf(eb, hb, acc);
            acc = fmaf(ec, hc, acc);
            acc = fmaf(ed, hd, acc);
        }
        for (; k < cnt1; k++) {
            float ex = __shfl(x1, k, 64);
            int s = __shfl(c1, k, 64);
            acc = fmaf(ex, H[(size_t)s * 64 + lane], acc);
        }
        for (int j = beg + 128; j < end; j++) {  // cold path gather
            int s = col[j];
            float t = AL[s] + ar_i;
            t = t > 0.f ? t : NEG_SLOPE * t;
            float ex = __expf(t - mx);
            acc = fmaf(ex, H[(size_t)s * 64 + lane], acc);
        }
    }
    float o = acc / (dl + EPS);
    OUT[(size_t)nidx * 64 + lane] = o > 0.f ? o : 0.f;  // fused relu
}

// ---- h3 @ Wp1 + bp1 -> p ; p @ Wp2 + bp2 -> q ; log_softmax(q) ----
__global__ __launch_bounds__(256) void post_kernel(const float* __restrict__ H3,
                                                   const float* __restrict__ Wp1,
                                                   const float* __restrict__ bp1,
                                                   const float* __restrict__ Wp2,
                                                   const float* __restrict__ bp2,
                                                   float* __restrict__ OUT, int n) {
    __shared__ float W1l[64 * 64];
    __shared__ float W2l[64 * 64];
    __shared__ __align__(16) float stage[4][64];
    int tid = threadIdx.x;
    for (int i = tid; i < 64 * 64; i += 256) {
        W1l[i] = Wp1[i];
        int k = i >> 6, jj = i & 63;
        W2l[i] = (jj < OUT_DIM) ? Wp2[k * OUT_DIM + jj] : 0.f;
    }
    __syncthreads();
    int lane = tid & 63, wv = tid >> 6;
    float b1 = bp1[lane];
    float b2 = (lane < OUT_DIM) ? bp2[lane] : 0.f;
    for (int nidx = blockIdx.x * 4 + wv; nidx < n; nidx += gridDim.x * 4) {
        float h = H3[(size_t)nidx * 64 + lane];
        stage[wv][lane] = h;
        float p = b1;
#pragma unroll 8
        for (int k4 = 0; k4 < 64; k4 += 4) {
            float4 hv = *(const float4*)&stage[wv][k4];
            p = fmaf(hv.x, W1l[(k4 + 0) * 64 + lane], p);
            p = fmaf(hv.y, W1l[(k4 + 1) * 64 + lane], p);
            p = fmaf(hv.z, W1l[(k4 + 2) * 64 + lane], p);
            p = fmaf(hv.w, W1l[(k4 + 3) * 64 + lane], p);
        }
        stage[wv][lane] = p;  // wave-synchronous overwrite after all reads
        float q = b2;
#pragma unroll 8
        for (int k4 = 0; k4 < 64; k4 += 4) {
            float4 pv = *(const float4*)&stage[wv][k4];
            q = fmaf(pv.x, W2l[(k4 + 0) * 64 + lane], q);
            q = fmaf(pv.y, W2l[(k4 + 1) * 64 + lane], q);
            q = fmaf(pv.z, W2l[(k4 + 2) * 64 + lane], q);
            q = fmaf(pv.w, W2l[(k4 + 3) * 64 + lane], q);
        }
        float qm = (lane < OUT_DIM) ? q : -INFINITY;
        float mxv = qm;
#pragma unroll
        for (int o = 32; o; o >>= 1) mxv = fmaxf(mxv, __shfl_xor(mxv, o, 64));
        float ex = (lane < OUT_DIM) ? __expf(q - mxv) : 0.f;
        float s = ex;
#pragma unroll
        for (int o = 32; o; o >>= 1) s += __shfl_xor(s, o, 64);
        float r = q - mxv - __logf(s);
        if (lane < OUT_DIM) OUT[(size_t)nidx * OUT_DIM + lane] = r;
    }
}

extern "C" void kernel_launch(void* const* d_in, const int* in_sizes, int n_in,
                              void* d_out, int out_size, void* d_ws, size_t ws_size,
                              hipStream_t stream) {
    const float* x = (const float*)d_in[0];
    const int* ei = (const int*)d_in[1];
    const float* W0 = (const float*)d_in[2];
    const float* b0 = (const float*)d_in[3];
    const float* al0 = (const float*)d_in[4];
    const float* ar0 = (const float*)d_in[5];
    const float* W1 = (const float*)d_in[6];
    const float* b1 = (const float*)d_in[7];
    const float* al1 = (const float*)d_in[8];
    const float* ar1 = (const float*)d_in[9];
    const float* W2 = (const float*)d_in[10];
    const float* b2 = (const float*)d_in[11];
    const float* al2 = (const float*)d_in[12];
    const float* ar2 = (const float*)d_in[13];
    const float* Wp1 = (const float*)d_in[14];
    const float* bp1 = (const float*)d_in[15];
    const float* Wp2 = (const float*)d_in[16];
    const float* bp2 = (const float*)d_in[17];
    float* out = (float*)d_out;

    const int N = in_sizes[0] / IN_DIM;
    const int E = in_sizes[1] / 2;
    const int NBUCK = (N + BN - 1) >> BBITS;

    char* ws = (char*)d_ws;
    float* h0 = (float*)ws;      ws += (size_t)N * 64 * sizeof(float);
    float* h1 = (float*)ws;      ws += (size_t)N * 64 * sizeof(float);
    float* ALb = (float*)ws;     ws += (size_t)N * sizeof(float);
    float* ARb = (float*)ws;     ws += (size_t)N * sizeof(float);
    int* rowptr = (int*)ws;      ws += (size_t)(N + 1) * sizeof(int);
    int* col = (int*)ws;         ws += (size_t)E * sizeof(int);
    int* bcnt = (int*)ws;        ws += (size_t)NBUCK * sizeof(int);
    int* bbase = (int*)ws;       ws += (size_t)(NBUCK + 1) * sizeof(int);
    int* bfill = (int*)ws;       ws += (size_t)NBUCK * sizeof(int);
    // staging aliases h0/h1 region (dead until lin0 runs; E*8B <= N*256B)
    int2* stg = (int2*)h0;

    const int* src = ei;
    const int* dst = ei + E;

    // ---- build CSR by dst: two-level counting sort ----
    hipMemsetAsync(bcnt, 0, (size_t)NBUCK * sizeof(int), stream);
    bucket_count_kernel<<<256, 256, 0, stream>>>(dst, bcnt, E, NBUCK);
    bucket_scan_kernel<<<1, 64, 0, stream>>>(bcnt, bbase, bfill, NBUCK);
    bucket_scatter_kernel<<<256, 256, 0, stream>>>(src, dst, bfill, stg, E, NBUCK);
    bucket_place_kernel<<<NBUCK, 1024, 0, stream>>>(stg, bbase, rowptr, col, N, E);

    int agg_grid = (N + 3) / 4;

    // ---- layer 0 ----
    lin_kernel<IN_DIM><<<2048, 256, 0, stream>>>(x, W0, b0, al0, ar0, h0, ALb, ARb, N);
    agg_kernel<<<agg_grid, 256, 0, stream>>>(rowptr, col, ALb, ARb, h0, h1, N);
    // ---- layer 1 ----
    lin_kernel<HID><<<2048, 256, 0, stream>>>(h1, W1, b1, al1, ar1, h0, ALb, ARb, N);
    agg_kernel<<<agg_grid, 256, 0, stream>>>(rowptr, col, ALb, ARb, h0, h1, N);
    // ---- layer 2 ----
    lin_kernel<HID><<<2048, 256, 0, stream>>>(h1, W2, b2, al2, ar2, h0, ALb, ARb, N);
    agg_kernel<<<agg_grid, 256, 0, stream>>>(rowptr, col, ALb, ARb, h0, h1, N);
    // ---- post ----
    post_kernel<<<2048, 256, 0, stream>>>(h1, Wp1, bp1, Wp2, bp2, out, N);
}

// Round 3
// 424.058 us; speedup vs baseline: 1.7856x; 1.3568x over previous
//
#include <hip/hip_runtime.h>
#include <hip/hip_bf16.h>
#include <math.h>

// GNNStack: 3x GAT(heads=1, hid=64) + relu, then 64->64, 64->47, log_softmax.
//  - CSR build via two-level counting sort (no per-node global atomics).
//  - LIN/POST: register-tiled GEMMs. Block = 64-node tile; thread = (node,
//    16 cols); W rows read as float4 from LDS and reused across 16 nodes
//    (cuts DS instrs/node ~5x vs per-lane b32 W reads, which were the
//    R2 bottleneck: post_kernel 111us @ VALUBusy 29%).
//  - AGG: one wave per dst node; shfl-broadcast gather.

#define IN_DIM 128
#define HID 64
#define OUT_DIM 47
#define NEG_SLOPE 0.2f
#define EPS 1e-16f
#define BBITS 10
#define BN 1024
#define NBUCK_MAX 128

// ---- CSR build: bucket histogram ----
__global__ __launch_bounds__(256) void bucket_count_kernel(const int* __restrict__ dst,
                                                           int* __restrict__ bcnt,
                                                           int e, int nbuck) {
    __shared__ int h[NBUCK_MAX];
    int tid = threadIdx.x;
    if (tid < nbuck) h[tid] = 0;
    __syncthreads();
    int chunk = (e + gridDim.x - 1) / gridDim.x;
    int beg = blockIdx.x * chunk, end = min(e, beg + chunk);
    for (int i = beg + tid; i < end; i += 256) atomicAdd(&h[dst[i] >> BBITS], 1);
    __syncthreads();
    if (tid < nbuck && h[tid]) atomicAdd(&bcnt[tid], h[tid]);
}

__global__ void bucket_scan_kernel(const int* __restrict__ bcnt, int* __restrict__ bbase,
                                   int* __restrict__ bfill, int nbuck) {
    if (threadIdx.x == 0 && blockIdx.x == 0) {
        int run = 0;
        for (int i = 0; i < nbuck; i++) { bbase[i] = run; bfill[i] = run; run += bcnt[i]; }
        bbase[nbuck] = run;
    }
}

__global__ __launch_bounds__(256) void bucket_scatter_kernel(const int* __restrict__ src,
                                                             const int* __restrict__ dst,
                                                             int* __restrict__ bfill,
                                                             int2* __restrict__ stg,
                                                             int e, int nbuck) {
    __shared__ int lcnt[NBUCK_MAX], lfill[NBUCK_MAX];
    int tid = threadIdx.x;
    if (tid < nbuck) lcnt[tid] = 0;
    __syncthreads();
    int chunk = (e + gridDim.x - 1) / gridDim.x;
    int beg = blockIdx.x * chunk, end = min(e, beg + chunk);
    for (int i = beg + tid; i < end; i += 256) atomicAdd(&lcnt[dst[i] >> BBITS], 1);
    __syncthreads();
    if (tid < nbuck) lfill[tid] = lcnt[tid] ? atomicAdd(&bfill[tid], lcnt[tid]) : 0;
    __syncthreads();
    for (int i = beg + tid; i < end; i += 256) {
        int d = dst[i];
        int p = atomicAdd(&lfill[d >> BBITS], 1);
        stg[p] = make_int2(src[i], d);
    }
}

__global__ __launch_bounds__(1024) void bucket_place_kernel(const int2* __restrict__ stg,
                                                            const int* __restrict__ bbase,
                                                            int* __restrict__ rowptr,
                                                            int* __restrict__ col,
                                                            int n, int e) {
    __shared__ int lcnt[BN];
    __shared__ int lscan[BN];
    __shared__ int lfill[BN];
    int tid = threadIdx.x, b = blockIdx.x;
    int node0 = b << BBITS;
    int ebeg = bbase[b], eend = bbase[b + 1];
    lcnt[tid] = 0;
    __syncthreads();
    for (int j = ebeg + tid; j < eend; j += 1024) atomicAdd(&lcnt[stg[j].y - node0], 1);
    __syncthreads();
    int v = lcnt[tid];
    lscan[tid] = v;
    __syncthreads();
    for (int off = 1; off < 1024; off <<= 1) {
        int t = (tid >= off) ? lscan[tid - off] : 0;
        __syncthreads();
        lscan[tid] += t;
        __syncthreads();
    }
    int gbase = ebeg + lscan[tid] - v;
    if (node0 + tid < n) rowptr[node0 + tid] = gbase;
    lfill[tid] = gbase;
    __syncthreads();
    for (int j = ebeg + tid; j < eend; j += 1024) {
        int2 ed = stg[j];
        int p = atomicAdd(&lfill[ed.y - node0], 1);
        col[p] = ed.x;
    }
    if (b == 0 && tid == 0) rowptr[n] = e;
}

#define FMA16(H, WP, ACC)                                     \
    {                                                         \
        float4 w0_ = *(const float4*)(WP);                    \
        float4 w1_ = *(const float4*)((WP) + 4);              \
        float4 w2_ = *(const float4*)((WP) + 8);              \
        float4 w3_ = *(const float4*)((WP) + 12);             \
        ACC[0] = fmaf(H, w0_.x, ACC[0]);                      \
        ACC[1] = fmaf(H, w0_.y, ACC[1]);                      \
        ACC[2] = fmaf(H, w0_.z, ACC[2]);                      \
        ACC[3] = fmaf(H, w0_.w, ACC[3]);                      \
        ACC[4] = fmaf(H, w1_.x, ACC[4]);                      \
        ACC[5] = fmaf(H, w1_.y, ACC[5]);                      \
        ACC[6] = fmaf(H, w1_.z, ACC[6]);                      \
        ACC[7] = fmaf(H, w1_.w, ACC[7]);                      \
        ACC[8] = fmaf(H, w2_.x, ACC[8]);                      \
        ACC[9] = fmaf(H, w2_.y, ACC[9]);                      \
        ACC[10] = fmaf(H, w2_.z, ACC[10]);                    \
        ACC[11] = fmaf(H, w2_.w, ACC[11]);                    \
        ACC[12] = fmaf(H, w3_.x, ACC[12]);                    \
        ACC[13] = fmaf(H, w3_.y, ACC[13]);                    \
        ACC[14] = fmaf(H, w3_.z, ACC[14]);                    \
        ACC[15] = fmaf(H, w3_.w, ACC[15]);                    \
    }

// ---- tiled h = X @ W + b, alpha_l = h.attl, alpha_r = h.attr ----
template <int DIN>
__global__ __launch_bounds__(256) void lin_tiled_kernel(const float* __restrict__ X,
                                                        const float* __restrict__ W,
                                                        const float* __restrict__ B,
                                                        const float* __restrict__ attl,
                                                        const float* __restrict__ attr,
                                                        float* __restrict__ H,
                                                        float* __restrict__ AL,
                                                        float* __restrict__ AR,
                                                        int n, int ntiles) {
    constexpr int P = DIN + 4;  // pad: conflict-free Xl[r][k] column reads
    __shared__ float Wl[DIN * 64];
    __shared__ float Xl[64 * P];
    __shared__ float Bs[64], als[64], ars[64];
    int tid = threadIdx.x;
    for (int i = tid; i < DIN * 64; i += 256) Wl[i] = W[i];
    if (tid < 64) {
        Bs[tid] = B[tid];
        als[tid] = attl[tid];
        ars[tid] = attr[tid];
    }
    int r = tid >> 2, cg = (tid & 3) << 4;
    for (int tile = blockIdx.x; tile < ntiles; tile += gridDim.x) {
        __syncthreads();  // Xl reuse guard (also covers initial Wl load)
        int node0 = tile << 6;
        for (int idx = tid; idx < 16 * DIN; idx += 256) {
            int flat = idx << 2;
            int rr = flat / DIN, kk = flat % DIN;
            int gsrc = min(node0 + rr, n - 1);
            *(float4*)&Xl[rr * P + kk] = *(const float4*)&X[(size_t)gsrc * DIN + kk];
        }
        __syncthreads();
        float acc[16];
#pragma unroll
        for (int i = 0; i < 16; i++) acc[i] = Bs[cg + i];
#pragma unroll 4
        for (int k = 0; k < DIN; k++) {
            float h = Xl[r * P + k];
            FMA16(h, &Wl[k * 64 + cg], acc);
        }
        float pl = 0.f, pr = 0.f;
#pragma unroll
        for (int i = 0; i < 16; i++) {
            pl = fmaf(acc[i], als[cg + i], pl);
            pr = fmaf(acc[i], ars[cg + i], pr);
        }
        pl += __shfl_xor(pl, 1, 64);
        pl += __shfl_xor(pl, 2, 64);
        pr += __shfl_xor(pr, 1, 64);
        pr += __shfl_xor(pr, 2, 64);
        int node = node0 + r;
        if (node < n) {
            float4* hp = (float4*)&H[(size_t)node * 64 + cg];
            hp[0] = make_float4(acc[0], acc[1], acc[2], acc[3]);
            hp[1] = make_float4(acc[4], acc[5], acc[6], acc[7]);
            hp[2] = make_float4(acc[8], acc[9], acc[10], acc[11]);
            hp[3] = make_float4(acc[12], acc[13], acc[14], acc[15]);
            if ((tid & 3) == 0) {
                AL[node] = pl;
                AR[node] = pr;
            }
        }
    }
}

// ---- One wave per dst node: segment softmax + weighted aggregate + relu ----
__global__ __launch_bounds__(256) void agg_kernel(const int* __restrict__ rowptr,
                                                  const int* __restrict__ col,
                                                  const float* __restrict__ AL,
                                                  const float* __restrict__ AR,
                                                  const float* __restrict__ H,
                                                  float* __restrict__ OUT, int n) {
    int wv = threadIdx.x >> 6, lane = threadIdx.x & 63;
    int nidx = blockIdx.x * 4 + wv;
    if (nidx >= n) return;
    int beg = rowptr[nidx], end = rowptr[nidx + 1];
    int deg = end - beg;
    float ar_i = AR[nidx];
    int c0 = 0;
    float e0 = -INFINITY;
    if (lane < deg) {
        c0 = col[beg + lane];
        float t = AL[c0] + ar_i;
        e0 = t > 0.f ? t : NEG_SLOPE * t;
    }
    int c1 = 0;
    float e1 = -INFINITY;
    if (64 + lane < deg) {
        c1 = col[beg + 64 + lane];
        float t = AL[c1] + ar_i;
        e1 = t > 0.f ? t : NEG_SLOPE * t;
    }
    float mx = fmaxf(e0, e1);
    for (int j = beg + 128 + lane; j < end; j += 64) {
        float t = AL[col[j]] + ar_i;
        t = t > 0.f ? t : NEG_SLOPE * t;
        mx = fmaxf(mx, t);
    }
#pragma unroll
    for (int o = 32; o; o >>= 1) mx = fmaxf(mx, __shfl_xor(mx, o, 64));
    float x0 = (lane < deg) ? __expf(e0 - mx) : 0.f;
    float x1 = (64 + lane < deg) ? __expf(e1 - mx) : 0.f;
    float dl = x0 + x1;
    for (int j = beg + 128 + lane; j < end; j += 64) {
        float t = AL[col[j]] + ar_i;
        t = t > 0.f ? t : NEG_SLOPE * t;
        dl += __expf(t - mx);
    }
#pragma unroll
    for (int o = 32; o; o >>= 1) dl += __shfl_xor(dl, o, 64);
    float acc = 0.f;
    int cnt0 = deg < 64 ? deg : 64;
    int k = 0;
    for (; k + 4 <= cnt0; k += 4) {
        float ea = __shfl(x0, k, 64), eb = __shfl(x0, k + 1, 64);
        float ec = __shfl(x0, k + 2, 64), ed = __shfl(x0, k + 3, 64);
        int sa = __shfl(c0, k, 64), sb = __shfl(c0, k + 1, 64);
        int sc = __shfl(c0, k + 2, 64), sd = __shfl(c0, k + 3, 64);
        float ha = H[(size_t)sa * 64 + lane];
        float hb = H[(size_t)sb * 64 + lane];
        float hc = H[(size_t)sc * 64 + lane];
        float hd = H[(size_t)sd * 64 + lane];
        acc = fmaf(ea, ha, acc);
        acc = fmaf(eb, hb, acc);
        acc = fmaf(ec, hc, acc);
        acc = fmaf(ed, hd, acc);
    }
    for (; k < cnt0; k++) {
        float ex = __shfl(x0, k, 64);
        int s = __shfl(c0, k, 64);
        acc = fmaf(ex, H[(size_t)s * 64 + lane], acc);
    }
    if (deg > 64) {
        int cnt1 = deg - 64 < 64 ? deg - 64 : 64;
        k = 0;
        for (; k + 4 <= cnt1; k += 4) {
            float ea = __shfl(x1, k, 64), eb = __shfl(x1, k + 1, 64);
            float ec = __shfl(x1, k + 2, 64), ed = __shfl(x1, k + 3, 64);
            int sa = __shfl(c1, k, 64), sb = __shfl(c1, k + 1, 64);
            int sc = __shfl(c1, k + 2, 64), sd = __shfl(c1, k + 3, 64);
            float ha = H[(size_t)sa * 64 + lane];
            float hb = H[(size_t)sb * 64 + lane];
            float hc = H[(size_t)sc * 64 + lane];
            float hd = H[(size_t)sd * 64 + lane];
            acc = fmaf(ea, ha, acc);
            acc = fmaf(eb, hb, acc);
            acc = fmaf(ec, hc, acc);
            acc = fmaf(ed, hd, acc);
        }
        for (; k < cnt1; k++) {
            float ex = __shfl(x1, k, 64);
            int s = __shfl(c1, k, 64);
            acc = fmaf(ex, H[(size_t)s * 64 + lane], acc);
        }
        for (int j = beg + 128; j < end; j++) {
            int s = col[j];
            float t = AL[s] + ar_i;
            t = t > 0.f ? t : NEG_SLOPE * t;
            float ex = __expf(t - mx);
            acc = fmaf(ex, H[(size_t)s * 64 + lane], acc);
        }
    }
    float o = acc / (dl + EPS);
    OUT[(size_t)nidx * 64 + lane] = o > 0.f ? o : 0.f;  // fused relu
}

// ---- tiled post: h3 @ Wp1 + bp1 -> p ; p @ Wp2 + bp2 -> q ; log_softmax ----
__global__ __launch_bounds__(256) void post_tiled_kernel(const float* __restrict__ H3,
                                                         const float* __restrict__ Wp1,
                                                         const float* __restrict__ bp1,
                                                         const float* __restrict__ Wp2,
                                                         const float* __restrict__ bp2,
                                                         float* __restrict__ OUT,
                                                         int n, int ntiles) {
    constexpr int P = 68;
    __shared__ float W1l[64 * 64];
    __shared__ float W2l[64 * 64];  // cols >=47 zero-padded (stride 64)
    __shared__ float Hl[64 * P];
    __shared__ float b1s[64], b2s[64];
    int tid = threadIdx.x;
    for (int i = tid; i < 64 * 64; i += 256) {
        W1l[i] = Wp1[i];
        int k = i >> 6, jj = i & 63;
        W2l[i] = (jj < OUT_DIM) ? Wp2[k * OUT_DIM + jj] : 0.f;
    }
    if (tid < 64) {
        b1s[tid] = bp1[tid];
        b2s[tid] = (tid < OUT_DIM) ? bp2[tid] : 0.f;
    }
    int r = tid >> 2, cg = (tid & 3) << 4;
    for (int tile = blockIdx.x; tile < ntiles; tile += gridDim.x) {
        __syncthreads();  // Hl reuse guard (also covers initial W load)
        int node0 = tile << 6;
        for (int idx = tid; idx < 16 * 64; idx += 256) {
            int flat = idx << 2;
            int rr = flat >> 6, kk = flat & 63;
            int gsrc = min(node0 + rr, n - 1);
            *(float4*)&Hl[rr * P + kk] = *(const float4*)&H3[(size_t)gsrc * 64 + kk];
        }
        __syncthreads();
        // GEMM1: p = h @ W1 + b1
        float acc[16];
#pragma unroll
        for (int i = 0; i < 16; i++) acc[i] = b1s[cg + i];
#pragma unroll 4
        for (int k = 0; k < 64; k++) {
            float h = Hl[r * P + k];
            FMA16(h, &W1l[k * 64 + cg], acc);
        }
        // stage p back into Hl row r — same 4-lane group (same wave) owns the
        // row for both the GEMM1 reads and GEMM2 reads: wave-synchronous.
        *(float4*)&Hl[r * P + cg] = make_float4(acc[0], acc[1], acc[2], acc[3]);
        *(float4*)&Hl[r * P + cg + 4] = make_float4(acc[4], acc[5], acc[6], acc[7]);
        *(float4*)&Hl[r * P + cg + 8] = make_float4(acc[8], acc[9], acc[10], acc[11]);
        *(float4*)&Hl[r * P + cg + 12] = make_float4(acc[12], acc[13], acc[14], acc[15]);
        // GEMM2: q = p @ W2 + b2
        float acc2[16];
#pragma unroll
        for (int i = 0; i < 16; i++) acc2[i] = b2s[cg + i];
#pragma unroll 4
        for (int k = 0; k < 64; k++) {
            float p = Hl[r * P + k];
            FMA16(p, &W2l[k * 64 + cg], acc2);
        }
        // log_softmax over 47 valid cols (4-lane group reduction)
        float m = -INFINITY;
#pragma unroll
        for (int i = 0; i < 16; i++)
            if (cg + i < OUT_DIM) m = fmaxf(m, acc2[i]);
        m = fmaxf(m, __shfl_xor(m, 1, 64));
        m = fmaxf(m, __shfl_xor(m, 2, 64));
        float s = 0.f;
#pragma unroll
        for (int i = 0; i < 16; i++)
            if (cg + i < OUT_DIM) s += __expf(acc2[i] - m);
        s += __shfl_xor(s, 1, 64);
        s += __shfl_xor(s, 2, 64);
        float lg = m + __logf(s);
        int node = node0 + r;
        if (node < n) {
#pragma unroll
            for (int i = 0; i < 16; i++) {
                int j = cg + i;
                if (j < OUT_DIM) OUT[(size_t)node * OUT_DIM + j] = acc2[i] - lg;
            }
        }
    }
}

extern "C" void kernel_launch(void* const* d_in, const int* in_sizes, int n_in,
                              void* d_out, int out_size, void* d_ws, size_t ws_size,
                              hipStream_t stream) {
    const float* x = (const float*)d_in[0];
    const int* ei = (const int*)d_in[1];
    const float* W0 = (const float*)d_in[2];
    const float* b0 = (const float*)d_in[3];
    const float* al0 = (const float*)d_in[4];
    const float* ar0 = (const float*)d_in[5];
    const float* W1 = (const float*)d_in[6];
    const float* b1 = (const float*)d_in[7];
    const float* al1 = (const float*)d_in[8];
    const float* ar1 = (const float*)d_in[9];
    const float* W2 = (const float*)d_in[10];
    const float* b2 = (const float*)d_in[11];
    const float* al2 = (const float*)d_in[12];
    const float* ar2 = (const float*)d_in[13];
    const float* Wp1 = (const float*)d_in[14];
    const float* bp1 = (const float*)d_in[15];
    const float* Wp2 = (const float*)d_in[16];
    const float* bp2 = (const float*)d_in[17];
    float* out = (float*)d_out;

    const int N = in_sizes[0] / IN_DIM;
    const int E = in_sizes[1] / 2;
    const int NBUCK = (N + BN - 1) >> BBITS;
    const int NTILES = (N + 63) >> 6;

    char* ws = (char*)d_ws;
    float* h0 = (float*)ws;      ws += (size_t)N * 64 * sizeof(float);
    float* h1 = (float*)ws;      ws += (size_t)N * 64 * sizeof(float);
    float* ALb = (float*)ws;     ws += (size_t)N * sizeof(float);
    float* ARb = (float*)ws;     ws += (size_t)N * sizeof(float);
    int* rowptr = (int*)ws;      ws += (size_t)(N + 1) * sizeof(int);
    int* col = (int*)ws;         ws += (size_t)E * sizeof(int);
    int* bcnt = (int*)ws;        ws += (size_t)NBUCK * sizeof(int);
    int* bbase = (int*)ws;       ws += (size_t)(NBUCK + 1) * sizeof(int);
    int* bfill = (int*)ws;       ws += (size_t)NBUCK * sizeof(int);
    int2* stg = (int2*)h0;  // staging aliases h0 (dead until lin0 runs)

    const int* src = ei;
    const int* dst = ei + E;

    // ---- build CSR by dst: two-level counting sort ----
    hipMemsetAsync(bcnt, 0, (size_t)NBUCK * sizeof(int), stream);
    bucket_count_kernel<<<256, 256, 0, stream>>>(dst, bcnt, E, NBUCK);
    bucket_scan_kernel<<<1, 64, 0, stream>>>(bcnt, bbase, bfill, NBUCK);
    bucket_scatter_kernel<<<256, 256, 0, stream>>>(src, dst, bfill, stg, E, NBUCK);
    bucket_place_kernel<<<NBUCK, 1024, 0, stream>>>(stg, bbase, rowptr, col, N, E);

    int agg_grid = (N + 3) / 4;

    // ---- layer 0 ----
    lin_tiled_kernel<IN_DIM><<<512, 256, 0, stream>>>(x, W0, b0, al0, ar0, h0, ALb, ARb, N, NTILES);
    agg_kernel<<<agg_grid, 256, 0, stream>>>(rowptr, col, ALb, ARb, h0, h1, N);
    // ---- layer 1 ----
    lin_tiled_kernel<HID><<<1024, 256, 0, stream>>>(h1, W1, b1, al1, ar1, h0, ALb, ARb, N, NTILES);
    agg_kernel<<<agg_grid, 256, 0, stream>>>(rowptr, col, ALb, ARb, h0, h1, N);
    // ---- layer 2 ----
    lin_tiled_kernel<HID><<<1024, 256, 0, stream>>>(h1, W2, b2, al2, ar2, h0, ALb, ARb, N, NTILES);
    agg_kernel<<<agg_grid, 256, 0, stream>>>(rowptr, col, ALb, ARb, h0, h1, N);
    // ---- post ----
    post_tiled_kernel<<<768, 256, 0, stream>>>(h1, Wp1, bp1, Wp2, bp2, out, N, NTILES);
}

// Round 4
// 418.370 us; speedup vs baseline: 1.8099x; 1.0136x over previous
//
#include <hip/hip_runtime.h>
#include <hip/hip_bf16.h>
#include <math.h>

// GNNStack: 3x GAT(heads=1, hid=64) + relu, then 64->64, 64->47, log_softmax.
//  - CSR build via two-level counting sort (no per-node global atomics).
//  - LIN/POST: register-tiled GEMMs (thread = node x 16 cols, LDS W reuse).
//  - LIN writes H in bf16: H is consumed ONLY by agg's random gather, so this
//    halves the L2-miss gather traffic (R3: 186MB fetch/dispatch, 410MB
//    logical). Accumulation and attention logits stay fp32.
//  - AGG: one wave per dst node; shfl-broadcast gather, unroll 8 for MLP.

#define IN_DIM 128
#define HID 64
#define OUT_DIM 47
#define NEG_SLOPE 0.2f
#define EPS 1e-16f
#define BBITS 10
#define BN 1024
#define NBUCK_MAX 128

__device__ __forceinline__ float bf2f(ushort u) {
    union { unsigned int i; float f; } c;
    c.i = ((unsigned int)u) << 16;
    return c.f;
}

// ---- CSR build: bucket histogram ----
__global__ __launch_bounds__(256) void bucket_count_kernel(const int* __restrict__ dst,
                                                           int* __restrict__ bcnt,
                                                           int e, int nbuck) {
    __shared__ int h[NBUCK_MAX];
    int tid = threadIdx.x;
    if (tid < nbuck) h[tid] = 0;
    __syncthreads();
    int chunk = (e + gridDim.x - 1) / gridDim.x;
    int beg = blockIdx.x * chunk, end = min(e, beg + chunk);
    for (int i = beg + tid; i < end; i += 256) atomicAdd(&h[dst[i] >> BBITS], 1);
    __syncthreads();
    if (tid < nbuck && h[tid]) atomicAdd(&bcnt[tid], h[tid]);
}

__global__ void bucket_scan_kernel(const int* __restrict__ bcnt, int* __restrict__ bbase,
                                   int* __restrict__ bfill, int nbuck) {
    if (threadIdx.x == 0 && blockIdx.x == 0) {
        int run = 0;
        for (int i = 0; i < nbuck; i++) { bbase[i] = run; bfill[i] = run; run += bcnt[i]; }
        bbase[nbuck] = run;
    }
}

__global__ __launch_bounds__(256) void bucket_scatter_kernel(const int* __restrict__ src,
                                                             const int* __restrict__ dst,
                                                             int* __restrict__ bfill,
                                                             int2* __restrict__ stg,
                                                             int e, int nbuck) {
    __shared__ int lcnt[NBUCK_MAX], lfill[NBUCK_MAX];
    int tid = threadIdx.x;
    if (tid < nbuck) lcnt[tid] = 0;
    __syncthreads();
    int chunk = (e + gridDim.x - 1) / gridDim.x;
    int beg = blockIdx.x * chunk, end = min(e, beg + chunk);
    for (int i = beg + tid; i < end; i += 256) atomicAdd(&lcnt[dst[i] >> BBITS], 1);
    __syncthreads();
    if (tid < nbuck) lfill[tid] = lcnt[tid] ? atomicAdd(&bfill[tid], lcnt[tid]) : 0;
    __syncthreads();
    for (int i = beg + tid; i < end; i += 256) {
        int d = dst[i];
        int p = atomicAdd(&lfill[d >> BBITS], 1);
        stg[p] = make_int2(src[i], d);
    }
}

__global__ __launch_bounds__(1024) void bucket_place_kernel(const int2* __restrict__ stg,
                                                            const int* __restrict__ bbase,
                                                            int* __restrict__ rowptr,
                                                            int* __restrict__ col,
                                                            int n, int e) {
    __shared__ int lcnt[BN];
    __shared__ int lscan[BN];
    __shared__ int lfill[BN];
    int tid = threadIdx.x, b = blockIdx.x;
    int node0 = b << BBITS;
    int ebeg = bbase[b], eend = bbase[b + 1];
    lcnt[tid] = 0;
    __syncthreads();
    for (int j = ebeg + tid; j < eend; j += 1024) atomicAdd(&lcnt[stg[j].y - node0], 1);
    __syncthreads();
    int v = lcnt[tid];
    lscan[tid] = v;
    __syncthreads();
    for (int off = 1; off < 1024; off <<= 1) {
        int t = (tid >= off) ? lscan[tid - off] : 0;
        __syncthreads();
        lscan[tid] += t;
        __syncthreads();
    }
    int gbase = ebeg + lscan[tid] - v;
    if (node0 + tid < n) rowptr[node0 + tid] = gbase;
    lfill[tid] = gbase;
    __syncthreads();
    for (int j = ebeg + tid; j < eend; j += 1024) {
        int2 ed = stg[j];
        int p = atomicAdd(&lfill[ed.y - node0], 1);
        col[p] = ed.x;
    }
    if (b == 0 && tid == 0) rowptr[n] = e;
}

#define FMA16(H, WP, ACC)                                     \
    {                                                         \
        float4 w0_ = *(const float4*)(WP);                    \
        float4 w1_ = *(const float4*)((WP) + 4);              \
        float4 w2_ = *(const float4*)((WP) + 8);              \
        float4 w3_ = *(const float4*)((WP) + 12);             \
        ACC[0] = fmaf(H, w0_.x, ACC[0]);                      \
        ACC[1] = fmaf(H, w0_.y, ACC[1]);                      \
        ACC[2] = fmaf(H, w0_.z, ACC[2]);                      \
        ACC[3] = fmaf(H, w0_.w, ACC[3]);                      \
        ACC[4] = fmaf(H, w1_.x, ACC[4]);                      \
        ACC[5] = fmaf(H, w1_.y, ACC[5]);                      \
        ACC[6] = fmaf(H, w1_.z, ACC[6]);                      \
        ACC[7] = fmaf(H, w1_.w, ACC[7]);                      \
        ACC[8] = fmaf(H, w2_.x, ACC[8]);                      \
        ACC[9] = fmaf(H, w2_.y, ACC[9]);                      \
        ACC[10] = fmaf(H, w2_.z, ACC[10]);                    \
        ACC[11] = fmaf(H, w2_.w, ACC[11]);                    \
        ACC[12] = fmaf(H, w3_.x, ACC[12]);                    \
        ACC[13] = fmaf(H, w3_.y, ACC[13]);                    \
        ACC[14] = fmaf(H, w3_.z, ACC[14]);                    \
        ACC[15] = fmaf(H, w3_.w, ACC[15]);                    \
    }

// ---- tiled h = X @ W + b -> bf16 H, alpha_l = h.attl, alpha_r = h.attr ----
template <int DIN>
__global__ __launch_bounds__(256) void lin_tiled_kernel(const float* __restrict__ X,
                                                        const float* __restrict__ W,
                                                        const float* __restrict__ B,
                                                        const float* __restrict__ attl,
                                                        const float* __restrict__ attr,
                                                        ushort* __restrict__ Hbf,
                                                        float* __restrict__ AL,
                                                        float* __restrict__ AR,
                                                        int n, int ntiles) {
    constexpr int P = DIN + 4;  // pad: conflict-free Xl[r][k] column reads
    __shared__ float Wl[DIN * 64];
    __shared__ float Xl[64 * P];
    __shared__ float Bs[64], als[64], ars[64];
    int tid = threadIdx.x;
    for (int i = tid; i < DIN * 64; i += 256) Wl[i] = W[i];
    if (tid < 64) {
        Bs[tid] = B[tid];
        als[tid] = attl[tid];
        ars[tid] = attr[tid];
    }
    int r = tid >> 2, cg = (tid & 3) << 4;
    for (int tile = blockIdx.x; tile < ntiles; tile += gridDim.x) {
        __syncthreads();  // Xl reuse guard (also covers initial Wl load)
        int node0 = tile << 6;
        for (int idx = tid; idx < 16 * DIN; idx += 256) {
            int flat = idx << 2;
            int rr = flat / DIN, kk = flat % DIN;
            int gsrc = min(node0 + rr, n - 1);
            *(float4*)&Xl[rr * P + kk] = *(const float4*)&X[(size_t)gsrc * DIN + kk];
        }
        __syncthreads();
        float acc[16];
#pragma unroll
        for (int i = 0; i < 16; i++) acc[i] = Bs[cg + i];
#pragma unroll 4
        for (int k = 0; k < DIN; k++) {
            float h = Xl[r * P + k];
            FMA16(h, &Wl[k * 64 + cg], acc);
        }
        float pl = 0.f, pr = 0.f;
#pragma unroll
        for (int i = 0; i < 16; i++) {
            pl = fmaf(acc[i], als[cg + i], pl);
            pr = fmaf(acc[i], ars[cg + i], pr);
        }
        pl += __shfl_xor(pl, 1, 64);
        pl += __shfl_xor(pl, 2, 64);
        pr += __shfl_xor(pr, 1, 64);
        pr += __shfl_xor(pr, 2, 64);
        int node = node0 + r;
        if (node < n) {
            // pack 16 fp32 -> 16 bf16 (RNE) -> 2 x uint4
            unsigned int w[8];
#pragma unroll
            for (int i = 0; i < 8; i++) {
                __hip_bfloat16 lo = __float2bfloat16(acc[2 * i]);
                __hip_bfloat16 hi = __float2bfloat16(acc[2 * i + 1]);
                unsigned int lob = *(unsigned short*)&lo;
                unsigned int hib = *(unsigned short*)&hi;
                w[i] = lob | (hib << 16);
            }
            uint4* hp = (uint4*)&Hbf[(size_t)node * 64 + cg];
            hp[0] = make_uint4(w[0], w[1], w[2], w[3]);
            hp[1] = make_uint4(w[4], w[5], w[6], w[7]);
            if ((tid & 3) == 0) {
                AL[node] = pl;
                AR[node] = pr;
            }
        }
    }
}

// ---- One wave per dst node: segment softmax + weighted aggregate + relu ----
__global__ __launch_bounds__(256) void agg_kernel(const int* __restrict__ rowptr,
                                                  const int* __restrict__ col,
                                                  const float* __restrict__ AL,
                                                  const float* __restrict__ AR,
                                                  const ushort* __restrict__ Hbf,
                                                  float* __restrict__ OUT, int n) {
    int wv = threadIdx.x >> 6, lane = threadIdx.x & 63;
    int nidx = blockIdx.x * 4 + wv;
    if (nidx >= n) return;
    int beg = rowptr[nidx], end = rowptr[nidx + 1];
    int deg = end - beg;
    float ar_i = AR[nidx];
    int c0 = 0;
    float e0 = -INFINITY;
    if (lane < deg) {
        c0 = col[beg + lane];
        float t = AL[c0] + ar_i;
        e0 = t > 0.f ? t : NEG_SLOPE * t;
    }
    int c1 = 0;
    float e1 = -INFINITY;
    if (64 + lane < deg) {
        c1 = col[beg + 64 + lane];
        float t = AL[c1] + ar_i;
        e1 = t > 0.f ? t : NEG_SLOPE * t;
    }
    float mx = fmaxf(e0, e1);
    for (int j = beg + 128 + lane; j < end; j += 64) {
        float t = AL[col[j]] + ar_i;
        t = t > 0.f ? t : NEG_SLOPE * t;
        mx = fmaxf(mx, t);
    }
#pragma unroll
    for (int o = 32; o; o >>= 1) mx = fmaxf(mx, __shfl_xor(mx, o, 64));
    float x0 = (lane < deg) ? __expf(e0 - mx) : 0.f;
    float x1 = (64 + lane < deg) ? __expf(e1 - mx) : 0.f;
    float dl = x0 + x1;
    for (int j = beg + 128 + lane; j < end; j += 64) {
        float t = AL[col[j]] + ar_i;
        t = t > 0.f ? t : NEG_SLOPE * t;
        dl += __expf(t - mx);
    }
#pragma unroll
    for (int o = 32; o; o >>= 1) dl += __shfl_xor(dl, o, 64);
    // gather pass: serial over edges (unroll 8 for loads in flight),
    // vector over channels (lane = channel), bf16 H rows (128B/edge).
    float acc = 0.f;
    int cnt0 = deg < 64 ? deg : 64;
    int k = 0;
    for (; k + 8 <= cnt0; k += 8) {
        float ew[8];
        int sw[8];
#pragma unroll
        for (int t = 0; t < 8; t++) {
            ew[t] = __shfl(x0, k + t, 64);
            sw[t] = __shfl(c0, k + t, 64);
        }
        float hv[8];
#pragma unroll
        for (int t = 0; t < 8; t++) hv[t] = bf2f(Hbf[(size_t)sw[t] * 64 + lane]);
#pragma unroll
        for (int t = 0; t < 8; t++) acc = fmaf(ew[t], hv[t], acc);
    }
    for (; k < cnt0; k++) {
        float ex = __shfl(x0, k, 64);
        int s = __shfl(c0, k, 64);
        acc = fmaf(ex, bf2f(Hbf[(size_t)s * 64 + lane]), acc);
    }
    if (deg > 64) {
        int cnt1 = deg - 64 < 64 ? deg - 64 : 64;
        k = 0;
        for (; k + 4 <= cnt1; k += 4) {
            float ea = __shfl(x1, k, 64), eb = __shfl(x1, k + 1, 64);
            float ec = __shfl(x1, k + 2, 64), ed = __shfl(x1, k + 3, 64);
            int sa = __shfl(c1, k, 64), sb = __shfl(c1, k + 1, 64);
            int sc = __shfl(c1, k + 2, 64), sd = __shfl(c1, k + 3, 64);
            float ha = bf2f(Hbf[(size_t)sa * 64 + lane]);
            float hb = bf2f(Hbf[(size_t)sb * 64 + lane]);
            float hc = bf2f(Hbf[(size_t)sc * 64 + lane]);
            float hd = bf2f(Hbf[(size_t)sd * 64 + lane]);
            acc = fmaf(ea, ha, acc);
            acc = fmaf(eb, hb, acc);
            acc = fmaf(ec, hc, acc);
            acc = fmaf(ed, hd, acc);
        }
        for (; k < cnt1; k++) {
            float ex = __shfl(x1, k, 64);
            int s = __shfl(c1, k, 64);
            acc = fmaf(ex, bf2f(Hbf[(size_t)s * 64 + lane]), acc);
        }
        for (int j = beg + 128; j < end; j++) {
            int s = col[j];
            float t = AL[s] + ar_i;
            t = t > 0.f ? t : NEG_SLOPE * t;
            float ex = __expf(t - mx);
            acc = fmaf(ex, bf2f(Hbf[(size_t)s * 64 + lane]), acc);
        }
    }
    float o = acc / (dl + EPS);
    OUT[(size_t)nidx * 64 + lane] = o > 0.f ? o : 0.f;  // fused relu
}

// ---- tiled post: h3 @ Wp1 + bp1 -> p ; p @ Wp2 + bp2 -> q ; log_softmax ----
__global__ __launch_bounds__(256) void post_tiled_kernel(const float* __restrict__ H3,
                                                         const float* __restrict__ Wp1,
                                                         const float* __restrict__ bp1,
                                                         const float* __restrict__ Wp2,
                                                         const float* __restrict__ bp2,
                                                         float* __restrict__ OUT,
                                                         int n, int ntiles) {
    constexpr int P = 68;
    __shared__ float W1l[64 * 64];
    __shared__ float W2l[64 * 64];  // cols >=47 zero-padded (stride 64)
    __shared__ float Hl[64 * P];
    __shared__ float b1s[64], b2s[64];
    int tid = threadIdx.x;
    for (int i = tid; i < 64 * 64; i += 256) {
        W1l[i] = Wp1[i];
        int k = i >> 6, jj = i & 63;
        W2l[i] = (jj < OUT_DIM) ? Wp2[k * OUT_DIM + jj] : 0.f;
    }
    if (tid < 64) {
        b1s[tid] = bp1[tid];
        b2s[tid] = (tid < OUT_DIM) ? bp2[tid] : 0.f;
    }
    int r = tid >> 2, cg = (tid & 3) << 4;
    for (int tile = blockIdx.x; tile < ntiles; tile += gridDim.x) {
        __syncthreads();  // Hl reuse guard (also covers initial W load)
        int node0 = tile << 6;
        for (int idx = tid; idx < 16 * 64; idx += 256) {
            int flat = idx << 2;
            int rr = flat >> 6, kk = flat & 63;
            int gsrc = min(node0 + rr, n - 1);
            *(float4*)&Hl[rr * P + kk] = *(const float4*)&H3[(size_t)gsrc * 64 + kk];
        }
        __syncthreads();
        float acc[16];
#pragma unroll
        for (int i = 0; i < 16; i++) acc[i] = b1s[cg + i];
#pragma unroll 4
        for (int k = 0; k < 64; k++) {
            float h = Hl[r * P + k];
            FMA16(h, &W1l[k * 64 + cg], acc);
        }
        *(float4*)&Hl[r * P + cg] = make_float4(acc[0], acc[1], acc[2], acc[3]);
        *(float4*)&Hl[r * P + cg + 4] = make_float4(acc[4], acc[5], acc[6], acc[7]);
        *(float4*)&Hl[r * P + cg + 8] = make_float4(acc[8], acc[9], acc[10], acc[11]);
        *(float4*)&Hl[r * P + cg + 12] = make_float4(acc[12], acc[13], acc[14], acc[15]);
        float acc2[16];
#pragma unroll
        for (int i = 0; i < 16; i++) acc2[i] = b2s[cg + i];
#pragma unroll 4
        for (int k = 0; k < 64; k++) {
            float p = Hl[r * P + k];
            FMA16(p, &W2l[k * 64 + cg], acc2);
        }
        float m = -INFINITY;
#pragma unroll
        for (int i = 0; i < 16; i++)
            if (cg + i < OUT_DIM) m = fmaxf(m, acc2[i]);
        m = fmaxf(m, __shfl_xor(m, 1, 64));
        m = fmaxf(m, __shfl_xor(m, 2, 64));
        float s = 0.f;
#pragma unroll
        for (int i = 0; i < 16; i++)
            if (cg + i < OUT_DIM) s += __expf(acc2[i] - m);
        s += __shfl_xor(s, 1, 64);
        s += __shfl_xor(s, 2, 64);
        float lg = m + __logf(s);
        int node = node0 + r;
        if (node < n) {
#pragma unroll
            for (int i = 0; i < 16; i++) {
                int j = cg + i;
                if (j < OUT_DIM) OUT[(size_t)node * OUT_DIM + j] = acc2[i] - lg;
            }
        }
    }
}

extern "C" void kernel_launch(void* const* d_in, const int* in_sizes, int n_in,
                              void* d_out, int out_size, void* d_ws, size_t ws_size,
                              hipStream_t stream) {
    const float* x = (const float*)d_in[0];
    const int* ei = (const int*)d_in[1];
    const float* W0 = (const float*)d_in[2];
    const float* b0 = (const float*)d_in[3];
    const float* al0 = (const float*)d_in[4];
    const float* ar0 = (const float*)d_in[5];
    const float* W1 = (const float*)d_in[6];
    const float* b1 = (const float*)d_in[7];
    const float* al1 = (const float*)d_in[8];
    const float* ar1 = (const float*)d_in[9];
    const float* W2 = (const float*)d_in[10];
    const float* b2 = (const float*)d_in[11];
    const float* al2 = (const float*)d_in[12];
    const float* ar2 = (const float*)d_in[13];
    const float* Wp1 = (const float*)d_in[14];
    const float* bp1 = (const float*)d_in[15];
    const float* Wp2 = (const float*)d_in[16];
    const float* bp2 = (const float*)d_in[17];
    float* out = (float*)d_out;

    const int N = in_sizes[0] / IN_DIM;
    const int E = in_sizes[1] / 2;
    const int NBUCK = (N + BN - 1) >> BBITS;
    const int NTILES = (N + 63) >> 6;

    char* ws = (char*)d_ws;
    float* Hf = (float*)ws;      ws += (size_t)N * 64 * sizeof(float);   // agg out / lin in
    ushort* Hbf = (ushort*)ws;   ws += (size_t)N * 64 * sizeof(ushort);  // lin out / agg gather
    float* ALb = (float*)ws;     ws += (size_t)N * sizeof(float);
    float* ARb = (float*)ws;     ws += (size_t)N * sizeof(float);
    int* rowptr = (int*)ws;      ws += (size_t)(N + 1) * sizeof(int);
    int* col = (int*)ws;         ws += (size_t)E * sizeof(int);
    int* bcnt = (int*)ws;        ws += (size_t)NBUCK * sizeof(int);
    int* bbase = (int*)ws;       ws += (size_t)(NBUCK + 1) * sizeof(int);
    int* bfill = (int*)ws;       ws += (size_t)NBUCK * sizeof(int);
    int2* stg = (int2*)Hf;  // staging aliases Hf (first written by agg0, after place)

    const int* src = ei;
    const int* dst = ei + E;

    // ---- build CSR by dst: two-level counting sort ----
    hipMemsetAsync(bcnt, 0, (size_t)NBUCK * sizeof(int), stream);
    bucket_count_kernel<<<256, 256, 0, stream>>>(dst, bcnt, E, NBUCK);
    bucket_scan_kernel<<<1, 64, 0, stream>>>(bcnt, bbase, bfill, NBUCK);
    bucket_scatter_kernel<<<256, 256, 0, stream>>>(src, dst, bfill, stg, E, NBUCK);
    bucket_place_kernel<<<NBUCK, 1024, 0, stream>>>(stg, bbase, rowptr, col, N, E);

    int agg_grid = (N + 3) / 4;

    // ---- layer 0 ----
    lin_tiled_kernel<IN_DIM><<<512, 256, 0, stream>>>(x, W0, b0, al0, ar0, Hbf, ALb, ARb, N, NTILES);
    agg_kernel<<<agg_grid, 256, 0, stream>>>(rowptr, col, ALb, ARb, Hbf, Hf, N);
    // ---- layer 1 ----
    lin_tiled_kernel<HID><<<1024, 256, 0, stream>>>(Hf, W1, b1, al1, ar1, Hbf, ALb, ARb, N, NTILES);
    agg_kernel<<<agg_grid, 256, 0, stream>>>(rowptr, col, ALb, ARb, Hbf, Hf, N);
    // ---- layer 2 ----
    lin_tiled_kernel<HID><<<1024, 256, 0, stream>>>(Hf, W2, b2, al2, ar2, Hbf, ALb, ARb, N, NTILES);
    agg_kernel<<<agg_grid, 256, 0, stream>>>(rowptr, col, ALb, ARb, Hbf, Hf, N);
    // ---- post ----
    post_tiled_kernel<<<768, 256, 0, stream>>>(Hf, Wp1, bp1, Wp2, bp2, out, N, NTILES);
}

// Round 5
// 367.735 us; speedup vs baseline: 2.0591x; 1.1377x over previous
//
#include <hip/hip_runtime.h>
#include <hip/hip_bf16.h>
#include <math.h>

// GNNStack: 3x GAT(heads=1, hid=64) + relu, then 64->64, 64->47, log_softmax.
//  - CSR build via two-level counting sort (no per-node global atomics).
//  - LIN/POST: register-tiled GEMMs (thread = node x 16 cols, LDS W reuse).
//  - H stored bf16 (R4: halves gather bytes; agg turned out issue-bound).
//  - AGG R5: group-parallel gather — 4 groups x 16 lanes, 4 edges per step,
//    one per-lane-index bpermute broadcasts 4 edges at once, uint2 (4xbf16)
//    loads with 32-bit offsets. ~3.5 wave-instrs/edge vs ~13 in R4.

#define IN_DIM 128
#define HID 64
#define OUT_DIM 47
#define NEG_SLOPE 0.2f
#define EPS 1e-16f
#define BBITS 10
#define BN 1024
#define NBUCK_MAX 128

__device__ __forceinline__ float bflo(unsigned int d) {
    union { unsigned int i; float f; } c;
    c.i = d << 16;
    return c.f;
}
__device__ __forceinline__ float bfhi(unsigned int d) {
    union { unsigned int i; float f; } c;
    c.i = d & 0xffff0000u;
    return c.f;
}

// ---- CSR build: bucket histogram ----
__global__ __launch_bounds__(256) void bucket_count_kernel(const int* __restrict__ dst,
                                                           int* __restrict__ bcnt,
                                                           int e, int nbuck) {
    __shared__ int h[NBUCK_MAX];
    int tid = threadIdx.x;
    if (tid < nbuck) h[tid] = 0;
    __syncthreads();
    int chunk = (e + gridDim.x - 1) / gridDim.x;
    int beg = blockIdx.x * chunk, end = min(e, beg + chunk);
    for (int i = beg + tid; i < end; i += 256) atomicAdd(&h[dst[i] >> BBITS], 1);
    __syncthreads();
    if (tid < nbuck && h[tid]) atomicAdd(&bcnt[tid], h[tid]);
}

__global__ void bucket_scan_kernel(const int* __restrict__ bcnt, int* __restrict__ bbase,
                                   int* __restrict__ bfill, int nbuck) {
    if (threadIdx.x == 0 && blockIdx.x == 0) {
        int run = 0;
        for (int i = 0; i < nbuck; i++) { bbase[i] = run; bfill[i] = run; run += bcnt[i]; }
        bbase[nbuck] = run;
    }
}

__global__ __launch_bounds__(256) void bucket_scatter_kernel(const int* __restrict__ src,
                                                             const int* __restrict__ dst,
                                                             int* __restrict__ bfill,
                                                             int2* __restrict__ stg,
                                                             int e, int nbuck) {
    __shared__ int lcnt[NBUCK_MAX], lfill[NBUCK_MAX];
    int tid = threadIdx.x;
    if (tid < nbuck) lcnt[tid] = 0;
    __syncthreads();
    int chunk = (e + gridDim.x - 1) / gridDim.x;
    int beg = blockIdx.x * chunk, end = min(e, beg + chunk);
    for (int i = beg + tid; i < end; i += 256) atomicAdd(&lcnt[dst[i] >> BBITS], 1);
    __syncthreads();
    if (tid < nbuck) lfill[tid] = lcnt[tid] ? atomicAdd(&bfill[tid], lcnt[tid]) : 0;
    __syncthreads();
    for (int i = beg + tid; i < end; i += 256) {
        int d = dst[i];
        int p = atomicAdd(&lfill[d >> BBITS], 1);
        stg[p] = make_int2(src[i], d);
    }
}

__global__ __launch_bounds__(1024) void bucket_place_kernel(const int2* __restrict__ stg,
                                                            const int* __restrict__ bbase,
                                                            int* __restrict__ rowptr,
                                                            int* __restrict__ col,
                                                            int n, int e) {
    __shared__ int lcnt[BN];
    __shared__ int lscan[BN];
    __shared__ int lfill[BN];
    int tid = threadIdx.x, b = blockIdx.x;
    int node0 = b << BBITS;
    int ebeg = bbase[b], eend = bbase[b + 1];
    lcnt[tid] = 0;
    __syncthreads();
    for (int j = ebeg + tid; j < eend; j += 1024) atomicAdd(&lcnt[stg[j].y - node0], 1);
    __syncthreads();
    int v = lcnt[tid];
    lscan[tid] = v;
    __syncthreads();
    for (int off = 1; off < 1024; off <<= 1) {
        int t = (tid >= off) ? lscan[tid - off] : 0;
        __syncthreads();
        lscan[tid] += t;
        __syncthreads();
    }
    int gbase = ebeg + lscan[tid] - v;
    if (node0 + tid < n) rowptr[node0 + tid] = gbase;
    lfill[tid] = gbase;
    __syncthreads();
    for (int j = ebeg + tid; j < eend; j += 1024) {
        int2 ed = stg[j];
        int p = atomicAdd(&lfill[ed.y - node0], 1);
        col[p] = ed.x;
    }
    if (b == 0 && tid == 0) rowptr[n] = e;
}

#define FMA16(H, WP, ACC)                                     \
    {                                                         \
        float4 w0_ = *(const float4*)(WP);                    \
        float4 w1_ = *(const float4*)((WP) + 4);              \
        float4 w2_ = *(const float4*)((WP) + 8);              \
        float4 w3_ = *(const float4*)((WP) + 12);             \
        ACC[0] = fmaf(H, w0_.x, ACC[0]);                      \
        ACC[1] = fmaf(H, w0_.y, ACC[1]);                      \
        ACC[2] = fmaf(H, w0_.z, ACC[2]);                      \
        ACC[3] = fmaf(H, w0_.w, ACC[3]);                      \
        ACC[4] = fmaf(H, w1_.x, ACC[4]);                      \
        ACC[5] = fmaf(H, w1_.y, ACC[5]);                      \
        ACC[6] = fmaf(H, w1_.z, ACC[6]);                      \
        ACC[7] = fmaf(H, w1_.w, ACC[7]);                      \
        ACC[8] = fmaf(H, w2_.x, ACC[8]);                      \
        ACC[9] = fmaf(H, w2_.y, ACC[9]);                      \
        ACC[10] = fmaf(H, w2_.z, ACC[10]);                    \
        ACC[11] = fmaf(H, w2_.w, ACC[11]);                    \
        ACC[12] = fmaf(H, w3_.x, ACC[12]);                    \
        ACC[13] = fmaf(H, w3_.y, ACC[13]);                    \
        ACC[14] = fmaf(H, w3_.z, ACC[14]);                    \
        ACC[15] = fmaf(H, w3_.w, ACC[15]);                    \
    }

// ---- tiled h = X @ W + b -> bf16 H, alpha_l = h.attl, alpha_r = h.attr ----
template <int DIN>
__global__ __launch_bounds__(256) void lin_tiled_kernel(const float* __restrict__ X,
                                                        const float* __restrict__ W,
                                                        const float* __restrict__ B,
                                                        const float* __restrict__ attl,
                                                        const float* __restrict__ attr,
                                                        ushort* __restrict__ Hbf,
                                                        float* __restrict__ AL,
                                                        float* __restrict__ AR,
                                                        int n, int ntiles) {
    constexpr int P = DIN + 4;  // pad: conflict-free Xl[r][k] column reads
    __shared__ float Wl[DIN * 64];
    __shared__ float Xl[64 * P];
    __shared__ float Bs[64], als[64], ars[64];
    int tid = threadIdx.x;
    for (int i = tid; i < DIN * 64; i += 256) Wl[i] = W[i];
    if (tid < 64) {
        Bs[tid] = B[tid];
        als[tid] = attl[tid];
        ars[tid] = attr[tid];
    }
    int r = tid >> 2, cg = (tid & 3) << 4;
    for (int tile = blockIdx.x; tile < ntiles; tile += gridDim.x) {
        __syncthreads();  // Xl reuse guard (also covers initial Wl load)
        int node0 = tile << 6;
        for (int idx = tid; idx < 16 * DIN; idx += 256) {
            int flat = idx << 2;
            int rr = flat / DIN, kk = flat % DIN;
            int gsrc = min(node0 + rr, n - 1);
            *(float4*)&Xl[rr * P + kk] = *(const float4*)&X[(size_t)gsrc * DIN + kk];
        }
        __syncthreads();
        float acc[16];
#pragma unroll
        for (int i = 0; i < 16; i++) acc[i] = Bs[cg + i];
#pragma unroll 4
        for (int k = 0; k < DIN; k++) {
            float h = Xl[r * P + k];
            FMA16(h, &Wl[k * 64 + cg], acc);
        }
        float pl = 0.f, pr = 0.f;
#pragma unroll
        for (int i = 0; i < 16; i++) {
            pl = fmaf(acc[i], als[cg + i], pl);
            pr = fmaf(acc[i], ars[cg + i], pr);
        }
        pl += __shfl_xor(pl, 1, 64);
        pl += __shfl_xor(pl, 2, 64);
        pr += __shfl_xor(pr, 1, 64);
        pr += __shfl_xor(pr, 2, 64);
        int node = node0 + r;
        if (node < n) {
            unsigned int w[8];
#pragma unroll
            for (int i = 0; i < 8; i++) {
                __hip_bfloat16 lo = __float2bfloat16(acc[2 * i]);
                __hip_bfloat16 hi = __float2bfloat16(acc[2 * i + 1]);
                unsigned int lob = *(unsigned short*)&lo;
                unsigned int hib = *(unsigned short*)&hi;
                w[i] = lob | (hib << 16);
            }
            uint4* hp = (uint4*)&Hbf[(size_t)node * 64 + cg];
            hp[0] = make_uint4(w[0], w[1], w[2], w[3]);
            hp[1] = make_uint4(w[4], w[5], w[6], w[7]);
            if ((tid & 3) == 0) {
                AL[node] = pl;
                AR[node] = pr;
            }
        }
    }
}

// ---- One wave per dst node: segment softmax + group-parallel gather ----
__global__ __launch_bounds__(256) void agg_kernel(const int* __restrict__ rowptr,
                                                  const int* __restrict__ col,
                                                  const float* __restrict__ AL,
                                                  const float* __restrict__ AR,
                                                  const ushort* __restrict__ Hbf,
                                                  float* __restrict__ OUT, int n) {
    int wv = threadIdx.x >> 6, lane = threadIdx.x & 63;
    int nidx = blockIdx.x * 4 + wv;
    if (nidx >= n) return;
    int beg = rowptr[nidx], end = rowptr[nidx + 1];
    int deg = end - beg;
    float ar_i = AR[nidx];
    // lane-parallel: edges -> registers (chunks of 64), leaky-relu logits
    int c0 = 0;
    float e0 = -INFINITY;
    if (lane < deg) {
        c0 = col[beg + lane];
        float t = AL[c0] + ar_i;
        e0 = t > 0.f ? t : NEG_SLOPE * t;
    }
    int c1 = 0;
    float e1 = -INFINITY;
    if (64 + lane < deg) {
        c1 = col[beg + 64 + lane];
        float t = AL[c1] + ar_i;
        e1 = t > 0.f ? t : NEG_SLOPE * t;
    }
    float mx = fmaxf(e0, e1);
    for (int j = beg + 128 + lane; j < end; j += 64) {  // cold: deg>128
        float t = AL[col[j]] + ar_i;
        t = t > 0.f ? t : NEG_SLOPE * t;
        mx = fmaxf(mx, t);
    }
#pragma unroll
    for (int o = 32; o; o >>= 1) mx = fmaxf(mx, __shfl_xor(mx, o, 64));
    float x0 = (lane < deg) ? __expf(e0 - mx) : 0.f;
    float x1 = (64 + lane < deg) ? __expf(e1 - mx) : 0.f;
    float dl = x0 + x1;
    for (int j = beg + 128 + lane; j < end; j += 64) {  // cold: deg>128
        float t = AL[col[j]] + ar_i;
        t = t > 0.f ? t : NEG_SLOPE * t;
        dl += __expf(t - mx);
    }
#pragma unroll
    for (int o = 32; o; o >>= 1) dl += __shfl_xor(dl, o, 64);
    // group-parallel gather: group g = lane>>4 takes edge k+g; lane covers
    // channels (lane&15)*4..+3. Zero-weight pad lanes (x=0, c=0) are safe.
    int g = lane >> 4;
    unsigned int sub = (lane & 15) << 3;  // byte offset into 128B bf16 row
    float a0 = 0.f, a1 = 0.f, a2 = 0.f, a3 = 0.f;
    int kend0 = deg < 64 ? deg : 64;
    for (int k = 0; k < kend0; k += 8) {
        int i0 = k + g, i1 = k + 4 + g;
        float w0 = __shfl(x0, i0, 64);
        int s0 = __shfl(c0, i0, 64);
        float w1 = __shfl(x0, i1, 64);
        int s1 = __shfl(c0, i1, 64);
        uint2 d0 = *(const uint2*)((const char*)Hbf + ((((unsigned)s0) << 7) + sub));
        uint2 d1 = *(const uint2*)((const char*)Hbf + ((((unsigned)s1) << 7) + sub));
        a0 = fmaf(w0, bflo(d0.x), a0);
        a1 = fmaf(w0, bfhi(d0.x), a1);
        a2 = fmaf(w0, bflo(d0.y), a2);
        a3 = fmaf(w0, bfhi(d0.y), a3);
        a0 = fmaf(w1, bflo(d1.x), a0);
        a1 = fmaf(w1, bfhi(d1.x), a1);
        a2 = fmaf(w1, bflo(d1.y), a2);
        a3 = fmaf(w1, bfhi(d1.y), a3);
    }
    if (deg > 64) {
        int kend1 = deg - 64 < 64 ? deg - 64 : 64;
        for (int k = 0; k < kend1; k += 8) {
            int i0 = k + g, i1 = k + 4 + g;
            float w0 = __shfl(x1, i0, 64);
            int s0 = __shfl(c1, i0, 64);
            float w1 = __shfl(x1, i1, 64);
            int s1 = __shfl(c1, i1, 64);
            uint2 d0 = *(const uint2*)((const char*)Hbf + ((((unsigned)s0) << 7) + sub));
            uint2 d1 = *(const uint2*)((const char*)Hbf + ((((unsigned)s1) << 7) + sub));
            a0 = fmaf(w0, bflo(d0.x), a0);
            a1 = fmaf(w0, bfhi(d0.x), a1);
            a2 = fmaf(w0, bflo(d0.y), a2);
            a3 = fmaf(w0, bfhi(d0.y), a3);
            a0 = fmaf(w1, bflo(d1.x), a0);
            a1 = fmaf(w1, bfhi(d1.x), a1);
            a2 = fmaf(w1, bflo(d1.y), a2);
            a3 = fmaf(w1, bfhi(d1.y), a3);
        }
        for (int j = beg + 128; j < end; j++) {  // cold: deg>128 (all lanes)
            int s = col[j];
            float t = AL[s] + ar_i;
            t = t > 0.f ? t : NEG_SLOPE * t;
            float ex = __expf(t - mx);
            uint2 d = *(const uint2*)((const char*)Hbf + ((((unsigned)s) << 7) + sub));
            a0 = fmaf(ex, bflo(d.x), a0);
            a1 = fmaf(ex, bfhi(d.x), a1);
            a2 = fmaf(ex, bflo(d.y), a2);
            a3 = fmaf(ex, bfhi(d.y), a3);
        }
    }
    // cross-group reduction (xor 16, 32) then store from group 0
    a0 += __shfl_xor(a0, 16, 64);
    a0 += __shfl_xor(a0, 32, 64);
    a1 += __shfl_xor(a1, 16, 64);
    a1 += __shfl_xor(a1, 32, 64);
    a2 += __shfl_xor(a2, 16, 64);
    a2 += __shfl_xor(a2, 32, 64);
    a3 += __shfl_xor(a3, 16, 64);
    a3 += __shfl_xor(a3, 32, 64);
    if (g == 0) {
        float r = 1.0f / (dl + EPS);
        float o0 = a0 * r, o1 = a1 * r, o2 = a2 * r, o3 = a3 * r;
        o0 = o0 > 0.f ? o0 : 0.f;
        o1 = o1 > 0.f ? o1 : 0.f;
        o2 = o2 > 0.f ? o2 : 0.f;
        o3 = o3 > 0.f ? o3 : 0.f;
        *(float4*)((char*)OUT + (((size_t)nidx) << 8) + (sub << 1)) =
            make_float4(o0, o1, o2, o3);
    }
}

// ---- tiled post: h3 @ Wp1 + bp1 -> p ; p @ Wp2 + bp2 -> q ; log_softmax ----
__global__ __launch_bounds__(256) void post_tiled_kernel(const float* __restrict__ H3,
                                                         const float* __restrict__ Wp1,
                                                         const float* __restrict__ bp1,
                                                         const float* __restrict__ Wp2,
                                                         const float* __restrict__ bp2,
                                                         float* __restrict__ OUT,
                                                         int n, int ntiles) {
    constexpr int P = 68;
    __shared__ float W1l[64 * 64];
    __shared__ float W2l[64 * 64];  // cols >=47 zero-padded (stride 64)
    __shared__ float Hl[64 * P];
    __shared__ float b1s[64], b2s[64];
    int tid = threadIdx.x;
    for (int i = tid; i < 64 * 64; i += 256) {
        W1l[i] = Wp1[i];
        int k = i >> 6, jj = i & 63;
        W2l[i] = (jj < OUT_DIM) ? Wp2[k * OUT_DIM + jj] : 0.f;
    }
    if (tid < 64) {
        b1s[tid] = bp1[tid];
        b2s[tid] = (tid < OUT_DIM) ? bp2[tid] : 0.f;
    }
    int r = tid >> 2, cg = (tid & 3) << 4;
    for (int tile = blockIdx.x; tile < ntiles; tile += gridDim.x) {
        __syncthreads();  // Hl reuse guard (also covers initial W load)
        int node0 = tile << 6;
        for (int idx = tid; idx < 16 * 64; idx += 256) {
            int flat = idx << 2;
            int rr = flat >> 6, kk = flat & 63;
            int gsrc = min(node0 + rr, n - 1);
            *(float4*)&Hl[rr * P + kk] = *(const float4*)&H3[(size_t)gsrc * 64 + kk];
        }
        __syncthreads();
        float acc[16];
#pragma unroll
        for (int i = 0; i < 16; i++) acc[i] = b1s[cg + i];
#pragma unroll 4
        for (int k = 0; k < 64; k++) {
            float h = Hl[r * P + k];
            FMA16(h, &W1l[k * 64 + cg], acc);
        }
        *(float4*)&Hl[r * P + cg] = make_float4(acc[0], acc[1], acc[2], acc[3]);
        *(float4*)&Hl[r * P + cg + 4] = make_float4(acc[4], acc[5], acc[6], acc[7]);
        *(float4*)&Hl[r * P + cg + 8] = make_float4(acc[8], acc[9], acc[10], acc[11]);
        *(float4*)&Hl[r * P + cg + 12] = make_float4(acc[12], acc[13], acc[14], acc[15]);
        float acc2[16];
#pragma unroll
        for (int i = 0; i < 16; i++) acc2[i] = b2s[cg + i];
#pragma unroll 4
        for (int k = 0; k < 64; k++) {
            float p = Hl[r * P + k];
            FMA16(p, &W2l[k * 64 + cg], acc2);
        }
        float m = -INFINITY;
#pragma unroll
        for (int i = 0; i < 16; i++)
            if (cg + i < OUT_DIM) m = fmaxf(m, acc2[i]);
        m = fmaxf(m, __shfl_xor(m, 1, 64));
        m = fmaxf(m, __shfl_xor(m, 2, 64));
        float s = 0.f;
#pragma unroll
        for (int i = 0; i < 16; i++)
            if (cg + i < OUT_DIM) s += __expf(acc2[i] - m);
        s += __shfl_xor(s, 1, 64);
        s += __shfl_xor(s, 2, 64);
        float lg = m + __logf(s);
        int node = node0 + r;
        if (node < n) {
#pragma unroll
            for (int i = 0; i < 16; i++) {
                int j = cg + i;
                if (j < OUT_DIM) OUT[(size_t)node * OUT_DIM + j] = acc2[i] - lg;
            }
        }
    }
}

extern "C" void kernel_launch(void* const* d_in, const int* in_sizes, int n_in,
                              void* d_out, int out_size, void* d_ws, size_t ws_size,
                              hipStream_t stream) {
    const float* x = (const float*)d_in[0];
    const int* ei = (const int*)d_in[1];
    const float* W0 = (const float*)d_in[2];
    const float* b0 = (const float*)d_in[3];
    const float* al0 = (const float*)d_in[4];
    const float* ar0 = (const float*)d_in[5];
    const float* W1 = (const float*)d_in[6];
    const float* b1 = (const float*)d_in[7];
    const float* al1 = (const float*)d_in[8];
    const float* ar1 = (const float*)d_in[9];
    const float* W2 = (const float*)d_in[10];
    const float* b2 = (const float*)d_in[11];
    const float* al2 = (const float*)d_in[12];
    const float* ar2 = (const float*)d_in[13];
    const float* Wp1 = (const float*)d_in[14];
    const float* bp1 = (const float*)d_in[15];
    const float* Wp2 = (const float*)d_in[16];
    const float* bp2 = (const float*)d_in[17];
    float* out = (float*)d_out;

    const int N = in_sizes[0] / IN_DIM;
    const int E = in_sizes[1] / 2;
    const int NBUCK = (N + BN - 1) >> BBITS;
    const int NTILES = (N + 63) >> 6;

    char* ws = (char*)d_ws;
    float* Hf = (float*)ws;      ws += (size_t)N * 64 * sizeof(float);   // agg out / lin in
    ushort* Hbf = (ushort*)ws;   ws += (size_t)N * 64 * sizeof(ushort);  // lin out / agg gather
    float* ALb = (float*)ws;     ws += (size_t)N * sizeof(float);
    float* ARb = (float*)ws;     ws += (size_t)N * sizeof(float);
    int* rowptr = (int*)ws;      ws += (size_t)(N + 1) * sizeof(int);
    int* col = (int*)ws;         ws += (size_t)E * sizeof(int);
    int* bcnt = (int*)ws;        ws += (size_t)NBUCK * sizeof(int);
    int* bbase = (int*)ws;       ws += (size_t)(NBUCK + 1) * sizeof(int);
    int* bfill = (int*)ws;       ws += (size_t)NBUCK * sizeof(int);
    int2* stg = (int2*)Hf;  // staging aliases Hf (dead until agg0 writes it)

    const int* src = ei;
    const int* dst = ei + E;

    // ---- build CSR by dst: two-level counting sort ----
    hipMemsetAsync(bcnt, 0, (size_t)NBUCK * sizeof(int), stream);
    bucket_count_kernel<<<256, 256, 0, stream>>>(dst, bcnt, E, NBUCK);
    bucket_scan_kernel<<<1, 64, 0, stream>>>(bcnt, bbase, bfill, NBUCK);
    bucket_scatter_kernel<<<256, 256, 0, stream>>>(src, dst, bfill, stg, E, NBUCK);
    bucket_place_kernel<<<NBUCK, 1024, 0, stream>>>(stg, bbase, rowptr, col, N, E);

    int agg_grid = (N + 3) / 4;

    // ---- layer 0 ----
    lin_tiled_kernel<IN_DIM><<<512, 256, 0, stream>>>(x, W0, b0, al0, ar0, Hbf, ALb, ARb, N, NTILES);
    agg_kernel<<<agg_grid, 256, 0, stream>>>(rowptr, col, ALb, ARb, Hbf, Hf, N);
    // ---- layer 1 ----
    lin_tiled_kernel<HID><<<1024, 256, 0, stream>>>(Hf, W1, b1, al1, ar1, Hbf, ALb, ARb, N, NTILES);
    agg_kernel<<<agg_grid, 256, 0, stream>>>(rowptr, col, ALb, ARb, Hbf, Hf, N);
    // ---- layer 2 ----
    lin_tiled_kernel<HID><<<1024, 256, 0, stream>>>(Hf, W2, b2, al2, ar2, Hbf, ALb, ARb, N, NTILES);
    agg_kernel<<<agg_grid, 256, 0, stream>>>(rowptr, col, ALb, ARb, Hbf, Hf, N);
    // ---- post ----
    post_tiled_kernel<<<768, 256, 0, stream>>>(Hf, Wp1, bp1, Wp2, bp2, out, N, NTILES);
}